// Round 9
// baseline (383.164 us; speedup 1.0000x reference)
//
#include <hip/hip_runtime.h>
#include <hip/hip_bf16.h>
#include <math.h>

typedef unsigned short u16;
typedef unsigned int   u32;
using short8  = __attribute__((ext_vector_type(8))) short;
using f32x4   = __attribute__((ext_vector_type(4))) float;

static constexpr int NNODE = 50000;
static constexpr int NEDGE = 600000;
static constexpr float EPSC   = 0.1f;
static constexpr float GAMMAC = 0.1f;

static constexpr int NTILE = (NNODE + 63) / 64;    // 782 GEMM row-tiles
static constexpr int GH    = 128;                  // histogram slices / fill blocks
static constexpr int NRNG  = 12500;                // nodes per histogram pass
static constexpr int NWORD = NRNG / 2;             // 6250 packed u32 words
static constexpr int NPASS = 4;                    // 4 x 12500 = 50000

// ---- workspace layout (float-index offsets) ----
static constexpr long long O_DINV   = 0;                         // float 50000
static constexpr long long O_DEGI   = 50000;                     // int 50000
static constexpr long long O_ROWPTR = 100000;                    // int 50000
static constexpr long long O_GCUR   = 150004;                    // int 1
static constexpr long long O_ECSR   = 200260;                    // int2 600000
// bf16 weights
static constexpr long long O_WHB    = 1400260;                   // 32768 bf16
static constexpr long long O_G1TB   = O_WHB  + 16384;
static constexpr long long O_AW1B   = O_G1TB + 8192;
static constexpr long long O_W2B    = O_AW1B + 8192;
static constexpr long long O_AW2B   = O_W2B  + 4096;
static constexpr long long O_G2TB   = O_AW2B + 2048;
static constexpr long long O_WFCB   = O_G2TB + 2048;
// big buffers
static constexpr long long O_AGGB   = 3450004;                   // bf16 6.4M
static constexpr long long O_HB0    = O_AGGB + 3200000;          // bf16 6.4M
static constexpr long long O_HB1    = O_HB0  + 3200000;          // bf16 6.4M
static constexpr long long O_S0     = O_HB1  + 3200000;          // fp8 6.4M
static constexpr long long O_S1     = O_S0   + 1600000;          // fp8 6.4M
// CSR de-atomization scratch
static constexpr long long O_PART   = O_S1   + 1600000;          // u16 GH x 50000
static constexpr long long O_BASE   = O_PART + 3200000;          // u16 GH x 50000

__device__ __forceinline__ float bf2f(u16 u) {
    return __uint_as_float(((unsigned)u) << 16);
}
__device__ __forceinline__ u16 f2bf(float f) {
    unsigned u = __float_as_uint(f);
    return (u16)((u + 0x7FFFu + ((u >> 16) & 1u)) >> 16);
}
// fast tanh: (e^{2x}-1)/(e^{2x}+1), clamped
__device__ __forceinline__ float ftanh(float x) {
    float x2 = fminf(fmaxf(2.f * x, -30.f), 30.f);
    float e = __expf(x2);
    return (e - 1.f) * __builtin_amdgcn_rcpf(e + 1.f);
}
// fp8 e4m3 pack/decode
__device__ __forceinline__ u16 pk_fp8(float a, float b) {
    int pk = __builtin_amdgcn_cvt_pk_fp8_f32(a, b, 0, false);
    return (u16)(pk & 0xffff);
}
__device__ __forceinline__ void acc_fp8x4(float* a, u32 v, float w) {
    a[0] += __builtin_amdgcn_cvt_f32_fp8(v, 0) * w;
    a[1] += __builtin_amdgcn_cvt_f32_fp8(v, 1) * w;
    a[2] += __builtin_amdgcn_cvt_f32_fp8(v, 2) * w;
    a[3] += __builtin_amdgcn_cvt_f32_fp8(v, 3) * w;
}

// ---- weight prep + gcur zero ----
__global__ __launch_bounds__(256) void prep_kernel(
    const float* __restrict__ w_hid, const float* __restrict__ W_a1,
    const float* __restrict__ gcn1,  const float* __restrict__ w2,
    const float* __restrict__ W_a2,  const float* __restrict__ gcn2,
    const float* __restrict__ wfc,   float* __restrict__ ws)
{
    int j = blockIdx.x * 256 + threadIdx.x;
    if (j < 32768) { ((u16*)(ws+O_WHB))[j] = f2bf(w_hid[j]); return; } j -= 32768;
    if (j < 16384) { int r=j>>7, c=j&127; ((u16*)(ws+O_G1TB))[j] = f2bf(gcn1[c*128+r]); return; } j -= 16384;
    if (j < 16384) { int r=j>>7, c=j&127;
                     ((u16*)(ws+O_AW1B))[j] = f2bf(W_a1[r*128+c] - W_a1[c*128+r] - (r==c?GAMMAC:0.f));
                     return; } j -= 16384;
    if (j < 8192)  { ((u16*)(ws+O_W2B))[j] = f2bf(w2[j]); return; } j -= 8192;
    if (j < 4096)  { int r=j>>6, c=j&63;
                     ((u16*)(ws+O_AW2B))[j] = f2bf(W_a2[r*64+c] - W_a2[c*64+r] - (r==c?GAMMAC:0.f));
                     return; } j -= 4096;
    if (j < 4096)  { int r=j>>6, c=j&63; ((u16*)(ws+O_G2TB))[j] = f2bf(gcn2[c*64+r]); return; } j -= 4096;
    if (j < 2560)  { ((u16*)(ws+O_WFCB))[j] = f2bf(wfc[j]); return; } j -= 2560;
    if (j == 0)    { ((int*)(ws+O_GCUR))[0] = 0; }
}

// ---- alloc: sum partials -> degi/dinv/base16; rowptr via wave-scan (1 atomic/wave) ----
__global__ __launch_bounds__(256) void alloc_kernel(
    const u16* __restrict__ part, float* __restrict__ dinv,
    int* __restrict__ degi, int* __restrict__ rowptr,
    u16* __restrict__ base16, int* __restrict__ gcur)
{
    int i = blockIdx.x * 256 + threadIdx.x;
    int lane = threadIdx.x & 63;
    bool ok = i < NNODE;
    int deg = 0;
    if (ok) {
        int run = 0;
        #pragma unroll 4
        for (int g = 0; g < GH; ++g) {
            base16[(long long)g * NNODE + i] = (u16)run;
            run += part[(long long)g * NNODE + i];
        }
        deg = run;
        degi[i] = deg;
        dinv[i] = rsqrtf(1.0f + (float)deg);   // +1 self loop
    }
    // inclusive wave scan of deg; one global atomic per wave
    int run = deg;
    #pragma unroll
    for (int off = 1; off < 64; off <<= 1) {
        int v = __shfl_up(run, off);
        if (lane >= off) run += v;
    }
    int tot = __shfl(run, 63);
    int basep = 0;
    if (lane == 63) basep = atomicAdd(gcur, tot);
    basep = __shfl(basep, 63);
    if (ok) rowptr[i] = basep + run - deg;
}

// ---- fill: LDS-cursor ranks, zero fabric atomics ----
__global__ __launch_bounds__(256) void fill_kernel(
    const int* __restrict__ ei, const float* __restrict__ dinv,
    const int* __restrict__ rowptr, const u16* __restrict__ base16,
    int2* __restrict__ ecsr)
{
    __shared__ u32 cur[NWORD];
    const int g = blockIdx.x;
    const long long e0 = (long long)g * NEDGE / GH;
    const long long e1 = (long long)(g + 1) * NEDGE / GH;
    const u16* bb = base16 + (long long)g * NNODE;
    for (int pass = 0; pass < NPASS; ++pass) {
        const int nbase = pass * NRNG;
        for (int wi = threadIdx.x; wi < NWORD; wi += 256) cur[wi] = 0;
        __syncthreads();
        for (long long e = e0 + threadIdx.x; e < e1; e += 256) {
            int d = ei[NEDGE + e];
            int r = d - nbase;
            if ((unsigned)r < (unsigned)NRNG) {
                int s = ei[e];
                u32 old = atomicAdd(&cur[r >> 1], 1u << ((r & 1) * 16));
                int rank = (int)((old >> ((r & 1) * 16)) & 0xffffu);
                int slot = rowptr[d] + (int)bb[d] + rank;
                int2 v;
                v.x = s;
                v.y = __float_as_int(dinv[s]);   // dinv[d] applied in gather epilogue
                ecsr[slot] = v;
            }
        }
        __syncthreads();
    }
}

// ---- MFMA GEMM (single-B): x @ w_hid^T, EPI=1; blocks >= NTILE build deg partials ----
template<int KS, int NT, int AF32, int LOADACT, int EPI>
__global__ __launch_bounds__(256, 4) void mgemm(
    const void* __restrict__ Araw,
    const u16* __restrict__ Bt,
    const float* __restrict__ bias,
    float* __restrict__ outF,
    u16* __restrict__ outB,
    u16* __restrict__ outB8,
    int M, int Nn, int ldc,
    const int* __restrict__ ei,      // edge dst for deg partials (may be null)
    u16* __restrict__ partial)       // GH x NNODE u16 (may be null)
{
    constexpr int K    = KS * 32;
    constexpr int KCHU = (K > 128) ? 128 : K;
    constexpr int KC   = KCHU / 32;
    constexpr int NCH  = K / KCHU;
    constexpr int P    = KCHU + 8;
    constexpr int ROWS = NT * 16;
    constexpr int CW   = NT * 16 + 1;
    constexpr int BSZ  = ROWS * P * 2;
    constexpr int ASZ  = 64 * CW * 4;
    constexpr int SMEM = BSZ > ASZ ? BSZ : ASZ;   // 34816 >= 25000 hist bytes
    __shared__ __align__(16) char smem[SMEM];

    // deg-partial role: LDS histogram (u16 pair packed per u32), NO fabric atomics
    if (ei && blockIdx.x >= NTILE) {
        int g = blockIdx.x - NTILE;               // 0..GH-1
        u32* hist = (u32*)smem;
        const long long e0 = (long long)g * NEDGE / GH;
        const long long e1 = (long long)(g + 1) * NEDGE / GH;
        u16* part = partial + (long long)g * NNODE;
        for (int pass = 0; pass < NPASS; ++pass) {
            const int nbase = pass * NRNG;
            for (int wi = threadIdx.x; wi < NWORD; wi += 256) hist[wi] = 0;
            __syncthreads();
            for (long long e = e0 + threadIdx.x; e < e1; e += 256) {
                int d = ei[NEDGE + e];
                int r = d - nbase;
                if ((unsigned)r < (unsigned)NRNG)
                    atomicAdd(&hist[r >> 1], 1u << ((r & 1) * 16));
            }
            __syncthreads();
            for (int wi = threadIdx.x; wi < NWORD; wi += 256)
                *(u32*)&part[nbase + wi * 2] = hist[wi];
            __syncthreads();
        }
        return;
    }

    u16*   bl   = (u16*)smem;
    float* accL = (float*)smem;

    const int wave = threadIdx.x >> 6;
    const int lane = threadIdx.x & 63;
    const int m = lane & 15, q = lane >> 4;
    const int rowbase = blockIdx.x * 64 + wave * 16;
    const int row = rowbase + m;
    const bool rok = row < M;
    const short8 z8 = {0,0,0,0,0,0,0,0};

    short8 af[KS];
    if (AF32) {
        const float* apf = (const float*)Araw + (long long)row * K;
        #pragma unroll
        for (int k = 0; k < KS; ++k) {
            short8 t = z8;
            if (rok) {
                const float4* p = (const float4*)(apf + (k * 4 + q) * 8);
                float4 a = p[0], b = p[1];
                t[0]=(short)f2bf(a.x); t[1]=(short)f2bf(a.y); t[2]=(short)f2bf(a.z); t[3]=(short)f2bf(a.w);
                t[4]=(short)f2bf(b.x); t[5]=(short)f2bf(b.y); t[6]=(short)f2bf(b.z); t[7]=(short)f2bf(b.w);
            }
            af[k] = t;
        }
    } else {
        const short8* ap = (const short8*)((const u16*)Araw + (long long)row * K);
        #pragma unroll
        for (int k = 0; k < KS; ++k) af[k] = rok ? ap[k * 4 + q] : z8;
    }
    if (LOADACT) {
        #pragma unroll
        for (int k = 0; k < KS; ++k)
            #pragma unroll
            for (int e = 0; e < 8; ++e) {
                float f = bf2f((u16)af[k][e]);
                f = f > 0.f ? f : 0.01f * f;
                af[k][e] = (short)f2bf(f);
            }
    }

    f32x4 acc[NT];
    #pragma unroll
    for (int j = 0; j < NT; ++j) acc[j] = (f32x4){0.f,0.f,0.f,0.f};

    for (int ch = 0; ch < NCH; ++ch) {
        if (ch) __syncthreads();
        constexpr int CHUNKS = ROWS * (KCHU / 8);
        for (int t = threadIdx.x; t < CHUNKS; t += 256) {
            int r = t / (KCHU / 8), c = t - r * (KCHU / 8);
            short8 v = z8;
            if (r < Nn) v = *(const short8*)&Bt[(long long)r * K + ch * KCHU + c * 8];
            *(short8*)&bl[r * P + c * 8] = v;
        }
        __syncthreads();
        #pragma unroll
        for (int j = 0; j < NT; ++j) {
            #pragma unroll
            for (int k = 0; k < KC; ++k) {
                short8 bf_ = *(const short8*)&bl[(j * 16 + m) * P + k * 32 + q * 8];
                acc[j] = __builtin_amdgcn_mfma_f32_16x16x32_bf16(af[ch * KC + k], bf_, acc[j], 0, 0, 0);
            }
        }
    }

    __syncthreads();
    #pragma unroll
    for (int j = 0; j < NT; ++j)
        #pragma unroll
        for (int r = 0; r < 4; ++r)
            accL[(wave * 16 + q * 4 + r) * CW + j * 16 + m] = acc[j][r];
    __syncthreads();

    const int c0 = lane * 2;
    if (c0 < NT * 16) {
        float2 bv = {0.f, 0.f};
        if (bias) {
            if (c0 < Nn)     bv.x = bias[c0];
            if (c0 + 1 < Nn) bv.y = bias[c0 + 1];
        }
        #pragma unroll
        for (int rl = 0; rl < 16; ++rl) {
            int rowD = rowbase + rl;
            if (rowD >= M) continue;
            float2 v = *(const float2*)&accL[(wave * 16 + rl) * CW + c0];
            long long o = (long long)rowD * ldc + c0;
            v.x += bv.x; v.y += bv.y;
            if (EPI == 1) {
                v.x = v.x > 0.f ? v.x : 0.01f * v.x;
                v.y = v.y > 0.f ? v.y : 0.01f * v.y;
            }
            if (c0 + 1 < Nn) {
                if (outB) { ushort2 ob; ob.x = f2bf(v.x); ob.y = f2bf(v.y);
                            *(ushort2*)&outB[o] = ob; }
                if (outB8) outB8[o >> 1] = pk_fp8(v.x, v.y);
                if (outF) { *(float2*)&outF[o] = v; }
            } else if (c0 < Nn) {
                if (outB) outB[o] = f2bf(v.x);
                if (outF) outF[o] = v.x;
            }
        }
    }
}

// ---- CSR gather (fp8 in, bf16 out), wave per node, dinv-hoisted, 4-unrolled ----
template<int HD>
__global__ __launch_bounds__(256) void gather_kernel(
    const int* __restrict__ rowptr, const int* __restrict__ degi,
    const int2* __restrict__ ecsr, const float* __restrict__ dinv,
    const u32* __restrict__ g8, u16* __restrict__ aggB)
{
    int node = (blockIdx.x * 256 + threadIdx.x) >> 6;
    int lane = threadIdx.x & 63;
    if (node >= NNODE) return;
    const int qr = lane >> 4, l4 = lane & 15;
    const int r0 = rowptr[node];
    const int r1 = r0 + degi[node];
    const float dn = dinv[node];
    constexpr int EL = (HD == 128) ? 8 : 4;

    float a[EL];
    #pragma unroll
    for (int i = 0; i < EL; ++i) a[i] = 0.f;
    if (qr == 0) {      // self term: dn * s_node (final *dn gives dn^2)
        if (HD == 128) {
            uint2 gv = ((const uint2*)g8)[(long long)node * 16 + l4];
            acc_fp8x4(a, gv.x, dn);
            acc_fp8x4(a + 4, gv.y, dn);
        } else {
            u32 gv = g8[(long long)node * 16 + l4];
            acc_fp8x4(a, gv, dn);
        }
    }

    for (int base = r0; base < r1; base += 64) {
        int idx = base + lane;
        int cs = 0; float cw = 0.f;
        if (idx < r1) { int2 ev = ecsr[idx]; cs = ev.x; cw = __int_as_float(ev.y); }
        int cnt = min(64, r1 - base);
        for (int j = 0; j < cnt; j += 16) {        // 4 independent loads in flight
            #pragma unroll
            for (int u = 0; u < 4; ++u) {
                int jj = j + u * 4 + qr;           // lanes past cnt carry cw=0
                int   s = __shfl(cs, jj);
                float w = __shfl(cw, jj);
                if (HD == 128) {
                    uint2 gv = ((const uint2*)g8)[(long long)s * 16 + l4];
                    acc_fp8x4(a, gv.x, w);
                    acc_fp8x4(a + 4, gv.y, w);
                } else {
                    u32 gv = g8[(long long)s * 16 + l4];
                    acc_fp8x4(a, gv, w);
                }
            }
        }
    }

    #pragma unroll
    for (int i = 0; i < EL; ++i) {
        a[i] += __shfl_xor(a[i], 16);
        a[i] += __shfl_xor(a[i], 32);
    }
    if (HD == 128) {
        float v0 = (qr == 0) ? a[0] : (qr == 1) ? a[2] : (qr == 2) ? a[4] : a[6];
        float v1 = (qr == 0) ? a[1] : (qr == 1) ? a[3] : (qr == 2) ? a[5] : a[7];
        v0 *= dn; v1 *= dn;
        long long o = (long long)node * 128 + l4 * 8 + qr * 2;
        ushort2 ob; ob.x = f2bf(v0); ob.y = f2bf(v1);
        *(ushort2*)&aggB[o] = ob;
    } else {
        float v = (qr == 0) ? a[0] : (qr == 1) ? a[1] : (qr == 2) ? a[2] : a[3];
        aggB[(long long)node * 64 + l4 * 4 + qr] = f2bf(v * dn);
    }
}

// ---- conv-step GEMM: acc = h@aW^T + (Âh)@G, epi h+eps*tanh(acc+b) ----
// TAIL=0: write h_new (bf16) + fp8 shadow.
// TAIL=1: additionally fuse h2 = leaky(leaky(h_new)@w2^T + b2).
template<int KS, int NT, int TAIL>
__global__ __launch_bounds__(256, TAIL ? 3 : 4) void mgemm_conv(
    const u16* __restrict__ hA,      // h  [M,K] bf16
    const u16* __restrict__ gA,      // Âh [M,K] bf16
    const u16* __restrict__ BtW,
    const u16* __restrict__ BtG,
    const float* __restrict__ bias,
    u16* __restrict__ outB,
    u16* __restrict__ outB8,         // fp8 shadow of output, may be null
    const u16* __restrict__ w2W,     // TAIL only: w2 [64,128] bf16
    const float* __restrict__ b2,    // TAIL only
    int M)
{
    constexpr int K    = KS * 32;
    constexpr int Nn   = NT * 16;
    constexpr int P    = K + 8;
    constexpr int CW   = Nn + 1;
    constexpr int BSZ  = Nn * P * 2;
    constexpr int ASZ  = 64 * CW * 4;
    constexpr int R1   = BSZ > ASZ ? BSZ : ASZ;
    constexpr int EXTRA = TAIL ? 64 * P * 2 : 0;
    __shared__ __align__(16) char smem[R1 + EXTRA];
    u16*   bl   = (u16*)smem;
    float* accL = (float*)smem;
    u16*   aggT = (u16*)(smem + R1);   // TAIL: leaky(h_new) tile

    const int wave = threadIdx.x >> 6;
    const int lane = threadIdx.x & 63;
    const int m = lane & 15, q = lane >> 4;
    const int rowbase = blockIdx.x * 64 + wave * 16;
    const int row = rowbase + m;
    const bool rok = row < M;
    const short8 z8 = {0,0,0,0,0,0,0,0};

    short8 af1[KS], af2[KS];
    {
        const short8* ap1 = (const short8*)(hA + (long long)row * K);
        const short8* ap2 = (const short8*)(gA + (long long)row * K);
        #pragma unroll
        for (int k = 0; k < KS; ++k) {
            af1[k] = rok ? ap1[k * 4 + q] : z8;
            af2[k] = rok ? ap2[k * 4 + q] : z8;
        }
    }

    f32x4 acc[NT];
    #pragma unroll
    for (int j = 0; j < NT; ++j) acc[j] = (f32x4){0.f,0.f,0.f,0.f};

    #pragma unroll
    for (int pass = 0; pass < 2; ++pass) {
        const u16* Bcur = pass ? BtG : BtW;
        if (pass) __syncthreads();
        constexpr int CHUNKS = Nn * (K / 8);
        for (int t = threadIdx.x; t < CHUNKS; t += 256) {
            int r = t / (K / 8), c = t - r * (K / 8);
            *(short8*)&bl[r * P + c * 8] = *(const short8*)&Bcur[(long long)r * K + c * 8];
        }
        __syncthreads();
        #pragma unroll
        for (int j = 0; j < NT; ++j) {
            #pragma unroll
            for (int k = 0; k < KS; ++k) {
                short8 bf_ = *(const short8*)&bl[(j * 16 + m) * P + k * 32 + q * 8];
                acc[j] = __builtin_amdgcn_mfma_f32_16x16x32_bf16(
                    pass ? af2[k] : af1[k], bf_, acc[j], 0, 0, 0);
            }
        }
    }

    __syncthreads();
    #pragma unroll
    for (int j = 0; j < NT; ++j)
        #pragma unroll
        for (int r = 0; r < 4; ++r)
            accL[(wave * 16 + q * 4 + r) * CW + j * 16 + m] = acc[j][r];
    __syncthreads();

    const int c0 = lane * 2;
    if (TAIL == 0) {
        if (c0 < Nn) {
            float2 bv = {bias[c0], bias[c0 + 1]};
            #pragma unroll
            for (int rl = 0; rl < 16; ++rl) {
                int rowD = rowbase + rl;
                if (rowD >= M) continue;
                float2 v = *(const float2*)&accL[(wave * 16 + rl) * CW + c0];
                long long o = (long long)rowD * Nn + c0;
                ushort2 hh = *(const ushort2*)&hA[o];
                float n0 = bf2f(hh.x) + EPSC * ftanh(v.x + bv.x);
                float n1 = bf2f(hh.y) + EPSC * ftanh(v.y + bv.y);
                ushort2 ob; ob.x = f2bf(n0); ob.y = f2bf(n1);
                *(ushort2*)&outB[o] = ob;
                if (outB8) outB8[o >> 1] = pk_fp8(n0, n1);
            }
        }
        return;
    }

    // ---- TAIL=1: leaky(h_new) -> LDS tile, then h2 = leaky(tile @ w2^T + b2) ----
    {
        float2 bv = {bias[c0], bias[c0 + 1]};
        #pragma unroll
        for (int rl = 0; rl < 16; ++rl) {
            int rowD = rowbase + rl;
            float n0 = 0.f, n1 = 0.f;
            if (rowD < M) {
                float2 v = *(const float2*)&accL[(wave * 16 + rl) * CW + c0];
                long long o = (long long)rowD * K + c0;
                ushort2 hh = *(const ushort2*)&hA[o];
                n0 = bf2f(hh.x) + EPSC * ftanh(v.x + bv.x);
                n1 = bf2f(hh.y) + EPSC * ftanh(v.y + bv.y);
                n0 = n0 > 0.f ? n0 : 0.01f * n0;
                n1 = n1 > 0.f ? n1 : 0.01f * n1;
            }
            ushort2 ob; ob.x = f2bf(n0); ob.y = f2bf(n1);
            *(ushort2*)&aggT[(wave * 16 + rl) * P + c0] = ob;
        }
    }
    __syncthreads();     // accL region about to be overwritten by w2 stage

    short8 af3[4];
    #pragma unroll
    for (int k = 0; k < 4; ++k)
        af3[k] = *(const short8*)&aggT[(wave * 16 + m) * P + k * 32 + q * 8];

    // stage w2 [64,128]
    {
        constexpr int CH2 = 64 * 16;
        for (int t = threadIdx.x; t < CH2; t += 256) {
            int r = t >> 4, c = t & 15;
            *(short8*)&bl[r * P + c * 8] = *(const short8*)&w2W[(long long)r * K + c * 8];
        }
    }
    __syncthreads();

    f32x4 acc2[4];
    #pragma unroll
    for (int j = 0; j < 4; ++j) acc2[j] = (f32x4){0.f,0.f,0.f,0.f};
    #pragma unroll
    for (int j = 0; j < 4; ++j)
        #pragma unroll
        for (int k = 0; k < 4; ++k) {
            short8 bf_ = *(const short8*)&bl[(j * 16 + m) * P + k * 32 + q * 8];
            acc2[j] = __builtin_amdgcn_mfma_f32_16x16x32_bf16(af3[k], bf_, acc2[j], 0, 0, 0);
        }

    __syncthreads();
    constexpr int CW2 = 65;
    #pragma unroll
    for (int j = 0; j < 4; ++j)
        #pragma unroll
        for (int r = 0; r < 4; ++r)
            accL[(wave * 16 + q * 4 + r) * CW2 + j * 16 + m] = acc2[j][r];
    __syncthreads();

    if (c0 < 64) {
        float2 bv = {b2[c0], b2[c0 + 1]};
        #pragma unroll
        for (int rl = 0; rl < 16; ++rl) {
            int rowD = rowbase + rl;
            if (rowD >= M) continue;
            float2 v = *(const float2*)&accL[(wave * 16 + rl) * CW2 + c0];
            v.x += bv.x; v.y += bv.y;
            v.x = v.x > 0.f ? v.x : 0.01f * v.x;
            v.y = v.y > 0.f ? v.y : 0.01f * v.y;
            long long o = (long long)rowD * 64 + c0;
            ushort2 ob; ob.x = f2bf(v.x); ob.y = f2bf(v.y);
            *(ushort2*)&outB[o] = ob;
            outB8[o >> 1] = pk_fp8(v.x, v.y);
        }
    }
}

// ---- fused conv2 + FC + log_softmax (agg from global) ----
__global__ __launch_bounds__(256, 4) void conv2fc(
    const u16* __restrict__ hA,      // h2 [M,64] bf16
    const u16* __restrict__ gA,      // Âh2 [M,64] bf16 (from gather<64>)
    const u16* __restrict__ BtW, const u16* __restrict__ BtG,
    const float* __restrict__ bias,
    const u16* __restrict__ wfcB, const float* __restrict__ bfc,
    float* __restrict__ outF, int M)
{
    constexpr int K  = 64, NT = 4, KS = 2;
    constexpr int P  = K + 8;                 // 72
    constexpr int CW = 65;
    constexpr int R1 = 64 * CW * 4;           // 16640
    __shared__ __align__(16) char smem[R1 + 64 * P * 2];
    u16*   bl   = (u16*)smem;
    float* accL = (float*)smem;
    u16*   aggT = (u16*)(smem + R1);

    const int wave = threadIdx.x >> 6;
    const int lane = threadIdx.x & 63;
    const int m = lane & 15, q = lane >> 4;
    const int rowbase = blockIdx.x * 64 + wave * 16;
    const int row = rowbase + m;
    const bool rok = row < M;
    const short8 z8 = {0,0,0,0,0,0,0,0};

    short8 af1[KS], af2[KS];
    {
        const short8* ap1 = (const short8*)(hA + (long long)row * K);
        const short8* ap2 = (const short8*)(gA + (long long)row * K);
        #pragma unroll
        for (int k = 0; k < KS; ++k) {
            af1[k] = rok ? ap1[k * 4 + q] : z8;
            af2[k] = rok ? ap2[k * 4 + q] : z8;
        }
    }

    f32x4 acc[NT];
    #pragma unroll
    for (int j = 0; j < NT; ++j) acc[j] = (f32x4){0.f,0.f,0.f,0.f};

    #pragma unroll
    for (int pass = 0; pass < 2; ++pass) {
        const u16* Bcur = pass ? BtG : BtW;
        if (pass) __syncthreads();
        constexpr int CHUNKS = 64 * (K / 8);      // 512
        for (int t = threadIdx.x; t < CHUNKS; t += 256) {
            int r = t >> 3, c = t & 7;
            *(short8*)&bl[r * P + c * 8] = *(const short8*)&Bcur[(long long)r * K + c * 8];
        }
        __syncthreads();
        #pragma unroll
        for (int j = 0; j < NT; ++j)
            #pragma unroll
            for (int k = 0; k < KS; ++k) {
                short8 bf_ = *(const short8*)&bl[(j * 16 + m) * P + k * 32 + q * 8];
                acc[j] = __builtin_amdgcn_mfma_f32_16x16x32_bf16(
                    pass ? af2[k] : af1[k], bf_, acc[j], 0, 0, 0);
            }
    }

    __syncthreads();
    #pragma unroll
    for (int j = 0; j < NT; ++j)
        #pragma unroll
        for (int r = 0; r < 4; ++r)
            accL[(wave * 16 + q * 4 + r) * CW + j * 16 + m] = acc[j][r];
    __syncthreads();

    // epilogue1: h2n = h2 + eps*tanh(acc + b_a2) -> aggT tile
    {
        const int c0 = lane * 2;
        float2 bv = {bias[c0 & 63], bias[(c0 + 1) & 63]};
        if (c0 < 64) {
            #pragma unroll
            for (int rl = 0; rl < 16; ++rl) {
                int rowD = rowbase + rl;
                float n0 = 0.f, n1 = 0.f;
                if (rowD < M) {
                    float2 v = *(const float2*)&accL[(wave * 16 + rl) * CW + c0];
                    long long o = (long long)rowD * 64 + c0;
                    ushort2 hh = *(const ushort2*)&hA[o];
                    n0 = bf2f(hh.x) + EPSC * ftanh(v.x + bv.x);
                    n1 = bf2f(hh.y) + EPSC * ftanh(v.y + bv.y);
                }
                ushort2 ob; ob.x = f2bf(n0); ob.y = f2bf(n1);
                *(ushort2*)&aggT[(wave * 16 + rl) * P + c0] = ob;
            }
        }
    }
    __syncthreads();   // accL region about to be restaged with wfc

    short8 af4[KS];
    #pragma unroll
    for (int k = 0; k < KS; ++k)
        af4[k] = *(const short8*)&aggT[(wave * 16 + m) * P + k * 32 + q * 8];

    // stage wfc [40,64], zero-pad rows 40..47 (NT=3 -> 48 rows)
    {
        constexpr int CHF = 48 * 8;
        for (int t = threadIdx.x; t < CHF; t += 256) {
            int r = t >> 3, c = t & 7;
            short8 v = z8;
            if (r < 40) v = *(const short8*)&wfcB[(long long)r * K + c * 8];
            *(short8*)&bl[r * P + c * 8] = v;
        }
    }
    __syncthreads();

    f32x4 acc3[3];
    #pragma unroll
    for (int j = 0; j < 3; ++j) acc3[j] = (f32x4){0.f,0.f,0.f,0.f};
    #pragma unroll
    for (int j = 0; j < 3; ++j)
        #pragma unroll
        for (int k = 0; k < KS; ++k) {
            short8 bf_ = *(const short8*)&bl[(j * 16 + m) * P + k * 32 + q * 8];
            acc3[j] = __builtin_amdgcn_mfma_f32_16x16x32_bf16(af4[k], bf_, acc3[j], 0, 0, 0);
        }

    __syncthreads();
    constexpr int CW3 = 49;
    #pragma unroll
    for (int j = 0; j < 3; ++j)
        #pragma unroll
        for (int r = 0; r < 4; ++r)
            accL[(wave * 16 + q * 4 + r) * CW3 + j * 16 + m] = acc3[j][r];
    __syncthreads();

    // fused log_softmax over 40 cols
    float mrow = 0.f, lrow = 0.f;
    if (lane < 16) {
        const float* rp = &accL[(wave * 16 + lane) * CW3];
        float mx = -1e30f;
        for (int c = 0; c < 40; ++c) mx = fmaxf(mx, rp[c] + bfc[c]);
        float s = 0.f;
        for (int c = 0; c < 40; ++c) s += expf(rp[c] + bfc[c] - mx);
        mrow = mx; lrow = logf(s);
    }
    for (int rl = 0; rl < 16; ++rl) {
        float mm = __shfl(mrow, rl);
        float ll = __shfl(lrow, rl);
        int rowD = rowbase + rl;
        if (rowD < M && lane < 40) {
            float v = accL[(wave * 16 + rl) * CW3 + lane] + bfc[lane];
            outF[(long long)rowD * 40 + lane] = v - mm - ll;
        }
    }
}

extern "C" void kernel_launch(void* const* d_in, const int* in_sizes, int n_in,
                              void* d_out, int out_size, void* d_ws, size_t ws_size,
                              hipStream_t stream) {
    const float* x     = (const float*)d_in[0];
    const int*   ei    = (const int*)d_in[1];
    const float* w_hid = (const float*)d_in[2];
    const float* b_hid = (const float*)d_in[3];
    const float* W_a1  = (const float*)d_in[4];
    const float* gcn1  = (const float*)d_in[5];
    const float* b_a1  = (const float*)d_in[6];
    const float* w2    = (const float*)d_in[7];
    const float* b2    = (const float*)d_in[8];
    const float* W_a2  = (const float*)d_in[9];
    const float* gcn2  = (const float*)d_in[10];
    const float* b_a2  = (const float*)d_in[11];
    const float* wfc   = (const float*)d_in[12];
    const float* bfc   = (const float*)d_in[13];
    float* ws = (float*)d_ws;
    float* out = (float*)d_out;

    float* dinv   = ws + O_DINV;
    int*   degi   = (int*)(ws + O_DEGI);
    int*   rowptr = (int*)(ws + O_ROWPTR);
    int*   gcur   = (int*)(ws + O_GCUR);
    int2*  ecsr   = (int2*)(ws + O_ECSR);
    u16* whB  = (u16*)(ws + O_WHB);
    u16* g1tB = (u16*)(ws + O_G1TB);
    u16* aw1B = (u16*)(ws + O_AW1B);
    u16* w2B  = (u16*)(ws + O_W2B);
    u16* aw2B = (u16*)(ws + O_AW2B);
    u16* g2tB = (u16*)(ws + O_G2TB);
    u16* wfcB = (u16*)(ws + O_WFCB);
    u16* aggB = (u16*)(ws + O_AGGB);
    u16* hB0  = (u16*)(ws + O_HB0);
    u16* hB1  = (u16*)(ws + O_HB1);
    u16* s0   = (u16*)(ws + O_S0);
    u16* s1   = (u16*)(ws + O_S1);
    u16* part = (u16*)(ws + O_PART);
    u16* base16 = (u16*)(ws + O_BASE);

    prep_kernel<<<(84481 + 255) / 256, 256, 0, stream>>>(
        w_hid, W_a1, gcn1, w2, W_a2, gcn2, wfc, ws);

    const int gatherBlocks = (NNODE * 64 + 255) / 256;   // 12500 (wave per node)

    // h = leaky_relu(x @ w_hid^T + b_hid) -> hB0 (+fp8 shadow s0);
    // blocks >= NTILE build per-slice degree partials via LDS histograms
    mgemm<8, 8, 1, 0, 1><<<NTILE + GH, 256, 0, stream>>>(
        x, whB, b_hid, nullptr, hB0, s0, NNODE, 128, 128, ei, part);

    alloc_kernel<<<(NNODE + 255) / 256, 256, 0, stream>>>(
        part, dinv, degi, rowptr, base16, gcur);
    fill_kernel<<<GH, 256, 0, stream>>>(ei, dinv, rowptr, base16, ecsr);

    // conv1 iter1
    gather_kernel<128><<<gatherBlocks, 256, 0, stream>>>(
        rowptr, degi, ecsr, dinv, (const u32*)s0, aggB);
    mgemm_conv<4, 8, 0><<<NTILE, 256, 0, stream>>>(
        hB0, aggB, aw1B, g1tB, b_a1, hB1, s1, nullptr, nullptr, NNODE);
    // conv1 iter2
    gather_kernel<128><<<gatherBlocks, 256, 0, stream>>>(
        rowptr, degi, ecsr, dinv, (const u32*)s1, aggB);
    mgemm_conv<4, 8, 0><<<NTILE, 256, 0, stream>>>(
        hB1, aggB, aw1B, g1tB, b_a1, hB0, s0, nullptr, nullptr, NNODE);
    // conv1 iter3 + fused h2 = leaky(leaky(h_new)@w2^T + b2) -> hB1 (+shadow s1)
    gather_kernel<128><<<gatherBlocks, 256, 0, stream>>>(
        rowptr, degi, ecsr, dinv, (const u32*)s0, aggB);
    mgemm_conv<4, 8, 1><<<NTILE, 256, 0, stream>>>(
        hB0, aggB, aw1B, g1tB, b_a1, hB1, s1, w2B, b2, NNODE);

    // conv2 + fc + log_softmax
    gather_kernel<64><<<gatherBlocks, 256, 0, stream>>>(
        rowptr, degi, ecsr, dinv, (const u32*)s1, aggB);
    conv2fc<<<NTILE, 256, 0, stream>>>(
        hB1, aggB, aw2B, g2tB, b_a2, wfcB, bfc, out, NNODE);
}

// Round 10
// 362.937 us; speedup vs baseline: 1.0557x; 1.0557x over previous
//
#include <hip/hip_runtime.h>
#include <hip/hip_bf16.h>
#include <math.h>

typedef unsigned short u16;
typedef unsigned int   u32;
using short8  = __attribute__((ext_vector_type(8))) short;
using f32x4   = __attribute__((ext_vector_type(4))) float;

static constexpr int NNODE = 50000;
static constexpr int NEDGE = 600000;
static constexpr float EPSC   = 0.1f;
static constexpr float GAMMAC = 0.1f;

static constexpr int NTILE = (NNODE + 63) / 64;    // 782 GEMM row-tiles
static constexpr int GH    = 128;                  // histogram slices
static constexpr int NRNG  = 12500;                // nodes per histogram pass
static constexpr int NWORD = NRNG / 2;             // 6250 packed u32 words
static constexpr int NPASS = 4;                    // 4 x 12500 = 50000

// ---- workspace layout (float-index offsets) ----
static constexpr long long O_DINV   = 0;                         // float 50000
static constexpr long long O_DEGI   = 50000;                     // int 50000
static constexpr long long O_ROWPTR = 100000;                    // int 50000
static constexpr long long O_GCUR   = 150004;                    // int 1
static constexpr long long O_ECSR   = 200260;                    // int2 600000
// bf16 weights
static constexpr long long O_WHB    = 1400260;                   // 32768 bf16
static constexpr long long O_G1TB   = O_WHB  + 16384;
static constexpr long long O_AW1B   = O_G1TB + 8192;
static constexpr long long O_W2B    = O_AW1B + 8192;
static constexpr long long O_AW2B   = O_W2B  + 4096;
static constexpr long long O_G2TB   = O_AW2B + 2048;
static constexpr long long O_WFCB   = O_G2TB + 2048;
// big buffers
static constexpr long long O_AGGB   = 3450004;                   // bf16 6.4M
static constexpr long long O_HB0    = O_AGGB + 3200000;          // bf16 6.4M
static constexpr long long O_HB1    = O_HB0  + 3200000;          // bf16 6.4M
static constexpr long long O_S0     = O_HB1  + 3200000;          // fp8 6.4M
static constexpr long long O_S1     = O_S0   + 1600000;          // fp8 6.4M
// CSR de-atomization scratch
static constexpr long long O_PART   = O_S1   + 1600000;          // u16 GH x 50000
static constexpr long long O_BASE   = O_PART + 3200000;          // u16 GH x 50000

__device__ __forceinline__ float bf2f(u16 u) {
    return __uint_as_float(((unsigned)u) << 16);
}
__device__ __forceinline__ u16 f2bf(float f) {
    unsigned u = __float_as_uint(f);
    return (u16)((u + 0x7FFFu + ((u >> 16) & 1u)) >> 16);
}
// fast tanh: (e^{2x}-1)/(e^{2x}+1), clamped
__device__ __forceinline__ float ftanh(float x) {
    float x2 = fminf(fmaxf(2.f * x, -30.f), 30.f);
    float e = __expf(x2);
    return (e - 1.f) * __builtin_amdgcn_rcpf(e + 1.f);
}
// fp8 e4m3 pack/decode
__device__ __forceinline__ u16 pk_fp8(float a, float b) {
    int pk = __builtin_amdgcn_cvt_pk_fp8_f32(a, b, 0, false);
    return (u16)(pk & 0xffff);
}
__device__ __forceinline__ void acc_fp8x4(float* a, u32 v, float w) {
    a[0] += __builtin_amdgcn_cvt_f32_fp8(v, 0) * w;
    a[1] += __builtin_amdgcn_cvt_f32_fp8(v, 1) * w;
    a[2] += __builtin_amdgcn_cvt_f32_fp8(v, 2) * w;
    a[3] += __builtin_amdgcn_cvt_f32_fp8(v, 3) * w;
}

// ---- weight prep + gcur zero ----
__global__ __launch_bounds__(256) void prep_kernel(
    const float* __restrict__ w_hid, const float* __restrict__ W_a1,
    const float* __restrict__ gcn1,  const float* __restrict__ w2,
    const float* __restrict__ W_a2,  const float* __restrict__ gcn2,
    const float* __restrict__ wfc,   float* __restrict__ ws)
{
    int j = blockIdx.x * 256 + threadIdx.x;
    if (j < 32768) { ((u16*)(ws+O_WHB))[j] = f2bf(w_hid[j]); return; } j -= 32768;
    if (j < 16384) { int r=j>>7, c=j&127; ((u16*)(ws+O_G1TB))[j] = f2bf(gcn1[c*128+r]); return; } j -= 16384;
    if (j < 16384) { int r=j>>7, c=j&127;
                     ((u16*)(ws+O_AW1B))[j] = f2bf(W_a1[r*128+c] - W_a1[c*128+r] - (r==c?GAMMAC:0.f));
                     return; } j -= 16384;
    if (j < 8192)  { ((u16*)(ws+O_W2B))[j] = f2bf(w2[j]); return; } j -= 8192;
    if (j < 4096)  { int r=j>>6, c=j&63;
                     ((u16*)(ws+O_AW2B))[j] = f2bf(W_a2[r*64+c] - W_a2[c*64+r] - (r==c?GAMMAC:0.f));
                     return; } j -= 4096;
    if (j < 4096)  { int r=j>>6, c=j&63; ((u16*)(ws+O_G2TB))[j] = f2bf(gcn2[c*64+r]); return; } j -= 4096;
    if (j < 2560)  { ((u16*)(ws+O_WFCB))[j] = f2bf(wfc[j]); return; } j -= 2560;
    if (j == 0)    { ((int*)(ws+O_GCUR))[0] = 0; }
}

// ---- alloc: sum partials -> degi/dinv/base16; rowptr via wave-scan (1 atomic/wave) ----
__global__ __launch_bounds__(256) void alloc_kernel(
    const u16* __restrict__ part, float* __restrict__ dinv,
    int* __restrict__ degi, int* __restrict__ rowptr,
    u16* __restrict__ base16, int* __restrict__ gcur)
{
    int i = blockIdx.x * 256 + threadIdx.x;
    int lane = threadIdx.x & 63;
    bool ok = i < NNODE;
    int deg = 0;
    if (ok) {
        int run = 0;
        #pragma unroll 4
        for (int g = 0; g < GH; ++g) {
            base16[(long long)g * NNODE + i] = (u16)run;
            run += part[(long long)g * NNODE + i];
        }
        deg = run;
        degi[i] = deg;
        dinv[i] = rsqrtf(1.0f + (float)deg);   // +1 self loop
    }
    // inclusive wave scan of deg; one global atomic per wave
    int run = deg;
    #pragma unroll
    for (int off = 1; off < 64; off <<= 1) {
        int v = __shfl_up(run, off);
        if (lane >= off) run += v;
    }
    int tot = __shfl(run, 63);
    int basep = 0;
    if (lane == 63) basep = atomicAdd(gcur, tot);
    basep = __shfl(basep, 63);
    if (ok) rowptr[i] = basep + run - deg;
}

// ---- fill: one (slice g, node-range pass) per block -> 512-way parallel,
//      zero fabric atomics. Valid: each (g,dst) group lives in exactly one pass.
__global__ __launch_bounds__(256) void fill_kernel(
    const int* __restrict__ ei, const float* __restrict__ dinv,
    const int* __restrict__ rowptr, const u16* __restrict__ base16,
    int2* __restrict__ ecsr)
{
    __shared__ u32 cur[NWORD];
    const int g    = blockIdx.x >> 2;            // slice
    const int pass = blockIdx.x & 3;             // node range
    const long long e0 = (long long)g * NEDGE / GH;
    const long long e1 = (long long)(g + 1) * NEDGE / GH;
    const u16* bb = base16 + (long long)g * NNODE;
    const int nbase = pass * NRNG;
    for (int wi = threadIdx.x; wi < NWORD; wi += 256) cur[wi] = 0;
    __syncthreads();
    for (long long e = e0 + threadIdx.x; e < e1; e += 256) {
        int d = ei[NEDGE + e];
        int r = d - nbase;
        if ((unsigned)r < (unsigned)NRNG) {
            int s = ei[e];
            u32 old = atomicAdd(&cur[r >> 1], 1u << ((r & 1) * 16));
            int rank = (int)((old >> ((r & 1) * 16)) & 0xffffu);
            int slot = rowptr[d] + (int)bb[d] + rank;
            int2 v;
            v.x = s;
            v.y = __float_as_int(dinv[s]);       // dinv[d] applied in gather epilogue
            ecsr[slot] = v;
        }
    }
}

// ---- MFMA GEMM (single-B): x @ w_hid^T, EPI=1; blocks >= NTILE build deg partials ----
template<int KS, int NT, int AF32, int LOADACT, int EPI>
__global__ __launch_bounds__(256, 4) void mgemm(
    const void* __restrict__ Araw,
    const u16* __restrict__ Bt,
    const float* __restrict__ bias,
    float* __restrict__ outF,
    u16* __restrict__ outB,
    u16* __restrict__ outB8,
    int M, int Nn, int ldc,
    const int* __restrict__ ei,      // edge dst for deg partials (may be null)
    u16* __restrict__ partial)       // GH x NNODE u16 (may be null)
{
    constexpr int K    = KS * 32;
    constexpr int KCHU = (K > 128) ? 128 : K;
    constexpr int KC   = KCHU / 32;
    constexpr int NCH  = K / KCHU;
    constexpr int P    = KCHU + 8;
    constexpr int ROWS = NT * 16;
    constexpr int CW   = NT * 16 + 1;
    constexpr int BSZ  = ROWS * P * 2;
    constexpr int ASZ  = 64 * CW * 4;
    constexpr int SMEM = BSZ > ASZ ? BSZ : ASZ;   // 34816 >= 25000 hist bytes
    __shared__ __align__(16) char smem[SMEM];

    // deg-partial role: LDS histogram (u16 pair packed per u32), NO fabric atomics
    if (ei && blockIdx.x >= NTILE) {
        int g = blockIdx.x - NTILE;               // 0..GH-1
        u32* hist = (u32*)smem;
        const long long e0 = (long long)g * NEDGE / GH;
        const long long e1 = (long long)(g + 1) * NEDGE / GH;
        u16* part = partial + (long long)g * NNODE;
        for (int pass = 0; pass < NPASS; ++pass) {
            const int nbase = pass * NRNG;
            for (int wi = threadIdx.x; wi < NWORD; wi += 256) hist[wi] = 0;
            __syncthreads();
            for (long long e = e0 + threadIdx.x; e < e1; e += 256) {
                int d = ei[NEDGE + e];
                int r = d - nbase;
                if ((unsigned)r < (unsigned)NRNG)
                    atomicAdd(&hist[r >> 1], 1u << ((r & 1) * 16));
            }
            __syncthreads();
            for (int wi = threadIdx.x; wi < NWORD; wi += 256)
                *(u32*)&part[nbase + wi * 2] = hist[wi];
            __syncthreads();
        }
        return;
    }

    u16*   bl   = (u16*)smem;
    float* accL = (float*)smem;

    const int wave = threadIdx.x >> 6;
    const int lane = threadIdx.x & 63;
    const int m = lane & 15, q = lane >> 4;
    const int rowbase = blockIdx.x * 64 + wave * 16;
    const int row = rowbase + m;
    const bool rok = row < M;
    const short8 z8 = {0,0,0,0,0,0,0,0};

    short8 af[KS];
    if (AF32) {
        const float* apf = (const float*)Araw + (long long)row * K;
        #pragma unroll
        for (int k = 0; k < KS; ++k) {
            short8 t = z8;
            if (rok) {
                const float4* p = (const float4*)(apf + (k * 4 + q) * 8);
                float4 a = p[0], b = p[1];
                t[0]=(short)f2bf(a.x); t[1]=(short)f2bf(a.y); t[2]=(short)f2bf(a.z); t[3]=(short)f2bf(a.w);
                t[4]=(short)f2bf(b.x); t[5]=(short)f2bf(b.y); t[6]=(short)f2bf(b.z); t[7]=(short)f2bf(b.w);
            }
            af[k] = t;
        }
    } else {
        const short8* ap = (const short8*)((const u16*)Araw + (long long)row * K);
        #pragma unroll
        for (int k = 0; k < KS; ++k) af[k] = rok ? ap[k * 4 + q] : z8;
    }
    if (LOADACT) {
        #pragma unroll
        for (int k = 0; k < KS; ++k)
            #pragma unroll
            for (int e = 0; e < 8; ++e) {
                float f = bf2f((u16)af[k][e]);
                f = f > 0.f ? f : 0.01f * f;
                af[k][e] = (short)f2bf(f);
            }
    }

    f32x4 acc[NT];
    #pragma unroll
    for (int j = 0; j < NT; ++j) acc[j] = (f32x4){0.f,0.f,0.f,0.f};

    for (int ch = 0; ch < NCH; ++ch) {
        if (ch) __syncthreads();
        constexpr int CHUNKS = ROWS * (KCHU / 8);
        for (int t = threadIdx.x; t < CHUNKS; t += 256) {
            int r = t / (KCHU / 8), c = t - r * (KCHU / 8);
            short8 v = z8;
            if (r < Nn) v = *(const short8*)&Bt[(long long)r * K + ch * KCHU + c * 8];
            *(short8*)&bl[r * P + c * 8] = v;
        }
        __syncthreads();
        #pragma unroll
        for (int j = 0; j < NT; ++j) {
            #pragma unroll
            for (int k = 0; k < KC; ++k) {
                short8 bf_ = *(const short8*)&bl[(j * 16 + m) * P + k * 32 + q * 8];
                acc[j] = __builtin_amdgcn_mfma_f32_16x16x32_bf16(af[ch * KC + k], bf_, acc[j], 0, 0, 0);
            }
        }
    }

    __syncthreads();
    #pragma unroll
    for (int j = 0; j < NT; ++j)
        #pragma unroll
        for (int r = 0; r < 4; ++r)
            accL[(wave * 16 + q * 4 + r) * CW + j * 16 + m] = acc[j][r];
    __syncthreads();

    const int c0 = lane * 2;
    if (c0 < NT * 16) {
        float2 bv = {0.f, 0.f};
        if (bias) {
            if (c0 < Nn)     bv.x = bias[c0];
            if (c0 + 1 < Nn) bv.y = bias[c0 + 1];
        }
        #pragma unroll
        for (int rl = 0; rl < 16; ++rl) {
            int rowD = rowbase + rl;
            if (rowD >= M) continue;
            float2 v = *(const float2*)&accL[(wave * 16 + rl) * CW + c0];
            long long o = (long long)rowD * ldc + c0;
            v.x += bv.x; v.y += bv.y;
            if (EPI == 1) {
                v.x = v.x > 0.f ? v.x : 0.01f * v.x;
                v.y = v.y > 0.f ? v.y : 0.01f * v.y;
            }
            if (c0 + 1 < Nn) {
                if (outB) { ushort2 ob; ob.x = f2bf(v.x); ob.y = f2bf(v.y);
                            *(ushort2*)&outB[o] = ob; }
                if (outB8) outB8[o >> 1] = pk_fp8(v.x, v.y);
                if (outF) { *(float2*)&outF[o] = v; }
            } else if (c0 < Nn) {
                if (outB) outB[o] = f2bf(v.x);
                if (outF) outF[o] = v.x;
            }
        }
    }
}

// ---- CSR gather (fp8 in, bf16 out), wave per node, dinv-hoisted, 4-unrolled ----
template<int HD>
__global__ __launch_bounds__(256) void gather_kernel(
    const int* __restrict__ rowptr, const int* __restrict__ degi,
    const int2* __restrict__ ecsr, const float* __restrict__ dinv,
    const u32* __restrict__ g8, u16* __restrict__ aggB)
{
    int node = (blockIdx.x * 256 + threadIdx.x) >> 6;
    int lane = threadIdx.x & 63;
    if (node >= NNODE) return;
    const int qr = lane >> 4, l4 = lane & 15;
    const int r0 = rowptr[node];
    const int r1 = r0 + degi[node];
    const float dn = dinv[node];
    constexpr int EL = (HD == 128) ? 8 : 4;

    float a[EL];
    #pragma unroll
    for (int i = 0; i < EL; ++i) a[i] = 0.f;
    if (qr == 0) {      // self term: dn * s_node (final *dn gives dn^2)
        if (HD == 128) {
            uint2 gv = ((const uint2*)g8)[(long long)node * 16 + l4];
            acc_fp8x4(a, gv.x, dn);
            acc_fp8x4(a + 4, gv.y, dn);
        } else {
            u32 gv = g8[(long long)node * 16 + l4];
            acc_fp8x4(a, gv, dn);
        }
    }

    for (int base = r0; base < r1; base += 64) {
        int idx = base + lane;
        int cs = 0; float cw = 0.f;
        if (idx < r1) { int2 ev = ecsr[idx]; cs = ev.x; cw = __int_as_float(ev.y); }
        int cnt = min(64, r1 - base);
        for (int j = 0; j < cnt; j += 16) {        // 4 independent loads in flight
            #pragma unroll
            for (int u = 0; u < 4; ++u) {
                int jj = j + u * 4 + qr;           // lanes past cnt carry cw=0
                int   s = __shfl(cs, jj);
                float w = __shfl(cw, jj);
                if (HD == 128) {
                    uint2 gv = ((const uint2*)g8)[(long long)s * 16 + l4];
                    acc_fp8x4(a, gv.x, w);
                    acc_fp8x4(a + 4, gv.y, w);
                } else {
                    u32 gv = g8[(long long)s * 16 + l4];
                    acc_fp8x4(a, gv, w);
                }
            }
        }
    }

    #pragma unroll
    for (int i = 0; i < EL; ++i) {
        a[i] += __shfl_xor(a[i], 16);
        a[i] += __shfl_xor(a[i], 32);
    }
    if (HD == 128) {
        float v0 = (qr == 0) ? a[0] : (qr == 1) ? a[2] : (qr == 2) ? a[4] : a[6];
        float v1 = (qr == 0) ? a[1] : (qr == 1) ? a[3] : (qr == 2) ? a[5] : a[7];
        v0 *= dn; v1 *= dn;
        long long o = (long long)node * 128 + l4 * 8 + qr * 2;
        ushort2 ob; ob.x = f2bf(v0); ob.y = f2bf(v1);
        *(ushort2*)&aggB[o] = ob;
    } else {
        float v = (qr == 0) ? a[0] : (qr == 1) ? a[1] : (qr == 2) ? a[2] : a[3];
        aggB[(long long)node * 64 + l4 * 4 + qr] = f2bf(v * dn);
    }
}

// ---- conv-step GEMM: acc = h@aW^T + (Âh)@G, epi h+eps*tanh(acc+b) ----
// TAIL=0: write h_new (bf16) + fp8 shadow.
// TAIL=1: additionally fuse h2 = leaky(leaky(h_new)@w2^T + b2).
template<int KS, int NT, int TAIL>
__global__ __launch_bounds__(256, TAIL ? 3 : 4) void mgemm_conv(
    const u16* __restrict__ hA,      // h  [M,K] bf16
    const u16* __restrict__ gA,      // Âh [M,K] bf16
    const u16* __restrict__ BtW,
    const u16* __restrict__ BtG,
    const float* __restrict__ bias,
    u16* __restrict__ outB,
    u16* __restrict__ outB8,         // fp8 shadow of output, may be null
    const u16* __restrict__ w2W,     // TAIL only: w2 [64,128] bf16
    const float* __restrict__ b2,    // TAIL only
    int M)
{
    constexpr int K    = KS * 32;
    constexpr int Nn   = NT * 16;
    constexpr int P    = K + 8;
    constexpr int CW   = Nn + 1;
    constexpr int BSZ  = Nn * P * 2;
    constexpr int ASZ  = 64 * CW * 4;
    constexpr int R1   = BSZ > ASZ ? BSZ : ASZ;
    constexpr int EXTRA = TAIL ? 64 * P * 2 : 0;
    __shared__ __align__(16) char smem[R1 + EXTRA];
    u16*   bl   = (u16*)smem;
    float* accL = (float*)smem;
    u16*   aggT = (u16*)(smem + R1);   // TAIL: leaky(h_new) tile

    const int wave = threadIdx.x >> 6;
    const int lane = threadIdx.x & 63;
    const int m = lane & 15, q = lane >> 4;
    const int rowbase = blockIdx.x * 64 + wave * 16;
    const int row = rowbase + m;
    const bool rok = row < M;
    const short8 z8 = {0,0,0,0,0,0,0,0};

    short8 af1[KS], af2[KS];
    {
        const short8* ap1 = (const short8*)(hA + (long long)row * K);
        const short8* ap2 = (const short8*)(gA + (long long)row * K);
        #pragma unroll
        for (int k = 0; k < KS; ++k) {
            af1[k] = rok ? ap1[k * 4 + q] : z8;
            af2[k] = rok ? ap2[k * 4 + q] : z8;
        }
    }

    f32x4 acc[NT];
    #pragma unroll
    for (int j = 0; j < NT; ++j) acc[j] = (f32x4){0.f,0.f,0.f,0.f};

    #pragma unroll
    for (int pass = 0; pass < 2; ++pass) {
        const u16* Bcur = pass ? BtG : BtW;
        if (pass) __syncthreads();
        constexpr int CHUNKS = Nn * (K / 8);
        for (int t = threadIdx.x; t < CHUNKS; t += 256) {
            int r = t / (K / 8), c = t - r * (K / 8);
            *(short8*)&bl[r * P + c * 8] = *(const short8*)&Bcur[(long long)r * K + c * 8];
        }
        __syncthreads();
        #pragma unroll
        for (int j = 0; j < NT; ++j) {
            #pragma unroll
            for (int k = 0; k < KS; ++k) {
                short8 bf_ = *(const short8*)&bl[(j * 16 + m) * P + k * 32 + q * 8];
                acc[j] = __builtin_amdgcn_mfma_f32_16x16x32_bf16(
                    pass ? af2[k] : af1[k], bf_, acc[j], 0, 0, 0);
            }
        }
    }

    __syncthreads();
    #pragma unroll
    for (int j = 0; j < NT; ++j)
        #pragma unroll
        for (int r = 0; r < 4; ++r)
            accL[(wave * 16 + q * 4 + r) * CW + j * 16 + m] = acc[j][r];
    __syncthreads();

    const int c0 = lane * 2;
    if (TAIL == 0) {
        if (c0 < Nn) {
            float2 bv = {bias[c0], bias[c0 + 1]};
            #pragma unroll
            for (int rl = 0; rl < 16; ++rl) {
                int rowD = rowbase + rl;
                if (rowD >= M) continue;
                float2 v = *(const float2*)&accL[(wave * 16 + rl) * CW + c0];
                long long o = (long long)rowD * Nn + c0;
                ushort2 hh = *(const ushort2*)&hA[o];
                float n0 = bf2f(hh.x) + EPSC * ftanh(v.x + bv.x);
                float n1 = bf2f(hh.y) + EPSC * ftanh(v.y + bv.y);
                ushort2 ob; ob.x = f2bf(n0); ob.y = f2bf(n1);
                *(ushort2*)&outB[o] = ob;
                if (outB8) outB8[o >> 1] = pk_fp8(n0, n1);
            }
        }
        return;
    }

    // ---- TAIL=1: leaky(h_new) -> LDS tile, then h2 = leaky(tile @ w2^T + b2) ----
    {
        float2 bv = {bias[c0], bias[c0 + 1]};
        #pragma unroll
        for (int rl = 0; rl < 16; ++rl) {
            int rowD = rowbase + rl;
            float n0 = 0.f, n1 = 0.f;
            if (rowD < M) {
                float2 v = *(const float2*)&accL[(wave * 16 + rl) * CW + c0];
                long long o = (long long)rowD * K + c0;
                ushort2 hh = *(const ushort2*)&hA[o];
                n0 = bf2f(hh.x) + EPSC * ftanh(v.x + bv.x);
                n1 = bf2f(hh.y) + EPSC * ftanh(v.y + bv.y);
                n0 = n0 > 0.f ? n0 : 0.01f * n0;
                n1 = n1 > 0.f ? n1 : 0.01f * n1;
            }
            ushort2 ob; ob.x = f2bf(n0); ob.y = f2bf(n1);
            *(ushort2*)&aggT[(wave * 16 + rl) * P + c0] = ob;
        }
    }
    __syncthreads();     // accL region about to be overwritten by w2 stage

    short8 af3[4];
    #pragma unroll
    for (int k = 0; k < 4; ++k)
        af3[k] = *(const short8*)&aggT[(wave * 16 + m) * P + k * 32 + q * 8];

    // stage w2 [64,128]
    {
        constexpr int CH2 = 64 * 16;
        for (int t = threadIdx.x; t < CH2; t += 256) {
            int r = t >> 4, c = t & 15;
            *(short8*)&bl[r * P + c * 8] = *(const short8*)&w2W[(long long)r * K + c * 8];
        }
    }
    __syncthreads();

    f32x4 acc2[4];
    #pragma unroll
    for (int j = 0; j < 4; ++j) acc2[j] = (f32x4){0.f,0.f,0.f,0.f};
    #pragma unroll
    for (int j = 0; j < 4; ++j)
        #pragma unroll
        for (int k = 0; k < 4; ++k) {
            short8 bf_ = *(const short8*)&bl[(j * 16 + m) * P + k * 32 + q * 8];
            acc2[j] = __builtin_amdgcn_mfma_f32_16x16x32_bf16(af3[k], bf_, acc2[j], 0, 0, 0);
        }

    __syncthreads();
    constexpr int CW2 = 65;
    #pragma unroll
    for (int j = 0; j < 4; ++j)
        #pragma unroll
        for (int r = 0; r < 4; ++r)
            accL[(wave * 16 + q * 4 + r) * CW2 + j * 16 + m] = acc2[j][r];
    __syncthreads();

    if (c0 < 64) {
        float2 bv = {b2[c0], b2[c0 + 1]};
        #pragma unroll
        for (int rl = 0; rl < 16; ++rl) {
            int rowD = rowbase + rl;
            if (rowD >= M) continue;
            float2 v = *(const float2*)&accL[(wave * 16 + rl) * CW2 + c0];
            v.x += bv.x; v.y += bv.y;
            v.x = v.x > 0.f ? v.x : 0.01f * v.x;
            v.y = v.y > 0.f ? v.y : 0.01f * v.y;
            long long o = (long long)rowD * 64 + c0;
            ushort2 ob; ob.x = f2bf(v.x); ob.y = f2bf(v.y);
            *(ushort2*)&outB[o] = ob;
            outB8[o >> 1] = pk_fp8(v.x, v.y);
        }
    }
}

// ---- fused conv2 + FC + log_softmax (agg from global) ----
__global__ __launch_bounds__(256, 4) void conv2fc(
    const u16* __restrict__ hA,      // h2 [M,64] bf16
    const u16* __restrict__ gA,      // Âh2 [M,64] bf16 (from gather<64>)
    const u16* __restrict__ BtW, const u16* __restrict__ BtG,
    const float* __restrict__ bias,
    const u16* __restrict__ wfcB, const float* __restrict__ bfc,
    float* __restrict__ outF, int M)
{
    constexpr int K  = 64, NT = 4, KS = 2;
    constexpr int P  = K + 8;                 // 72
    constexpr int CW = 65;
    constexpr int R1 = 64 * CW * 4;           // 16640
    __shared__ __align__(16) char smem[R1 + 64 * P * 2];
    u16*   bl   = (u16*)smem;
    float* accL = (float*)smem;
    u16*   aggT = (u16*)(smem + R1);

    const int wave = threadIdx.x >> 6;
    const int lane = threadIdx.x & 63;
    const int m = lane & 15, q = lane >> 4;
    const int rowbase = blockIdx.x * 64 + wave * 16;
    const int row = rowbase + m;
    const bool rok = row < M;
    const short8 z8 = {0,0,0,0,0,0,0,0};

    short8 af1[KS], af2[KS];
    {
        const short8* ap1 = (const short8*)(hA + (long long)row * K);
        const short8* ap2 = (const short8*)(gA + (long long)row * K);
        #pragma unroll
        for (int k = 0; k < KS; ++k) {
            af1[k] = rok ? ap1[k * 4 + q] : z8;
            af2[k] = rok ? ap2[k * 4 + q] : z8;
        }
    }

    f32x4 acc[NT];
    #pragma unroll
    for (int j = 0; j < NT; ++j) acc[j] = (f32x4){0.f,0.f,0.f,0.f};

    #pragma unroll
    for (int pass = 0; pass < 2; ++pass) {
        const u16* Bcur = pass ? BtG : BtW;
        if (pass) __syncthreads();
        constexpr int CHUNKS = 64 * (K / 8);      // 512
        for (int t = threadIdx.x; t < CHUNKS; t += 256) {
            int r = t >> 3, c = t & 7;
            *(short8*)&bl[r * P + c * 8] = *(const short8*)&Bcur[(long long)r * K + c * 8];
        }
        __syncthreads();
        #pragma unroll
        for (int j = 0; j < NT; ++j)
            #pragma unroll
            for (int k = 0; k < KS; ++k) {
                short8 bf_ = *(const short8*)&bl[(j * 16 + m) * P + k * 32 + q * 8];
                acc[j] = __builtin_amdgcn_mfma_f32_16x16x32_bf16(
                    pass ? af2[k] : af1[k], bf_, acc[j], 0, 0, 0);
            }
    }

    __syncthreads();
    #pragma unroll
    for (int j = 0; j < NT; ++j)
        #pragma unroll
        for (int r = 0; r < 4; ++r)
            accL[(wave * 16 + q * 4 + r) * CW + j * 16 + m] = acc[j][r];
    __syncthreads();

    // epilogue1: h2n = h2 + eps*tanh(acc + b_a2) -> aggT tile
    {
        const int c0 = lane * 2;
        float2 bv = {bias[c0 & 63], bias[(c0 + 1) & 63]};
        if (c0 < 64) {
            #pragma unroll
            for (int rl = 0; rl < 16; ++rl) {
                int rowD = rowbase + rl;
                float n0 = 0.f, n1 = 0.f;
                if (rowD < M) {
                    float2 v = *(const float2*)&accL[(wave * 16 + rl) * CW + c0];
                    long long o = (long long)rowD * 64 + c0;
                    ushort2 hh = *(const ushort2*)&hA[o];
                    n0 = bf2f(hh.x) + EPSC * ftanh(v.x + bv.x);
                    n1 = bf2f(hh.y) + EPSC * ftanh(v.y + bv.y);
                }
                ushort2 ob; ob.x = f2bf(n0); ob.y = f2bf(n1);
                *(ushort2*)&aggT[(wave * 16 + rl) * P + c0] = ob;
            }
        }
    }
    __syncthreads();   // accL region about to be restaged with wfc

    short8 af4[KS];
    #pragma unroll
    for (int k = 0; k < KS; ++k)
        af4[k] = *(const short8*)&aggT[(wave * 16 + m) * P + k * 32 + q * 8];

    // stage wfc [40,64], zero-pad rows 40..47 (NT=3 -> 48 rows)
    {
        constexpr int CHF = 48 * 8;
        for (int t = threadIdx.x; t < CHF; t += 256) {
            int r = t >> 3, c = t & 7;
            short8 v = z8;
            if (r < 40) v = *(const short8*)&wfcB[(long long)r * K + c * 8];
            *(short8*)&bl[r * P + c * 8] = v;
        }
    }
    __syncthreads();

    f32x4 acc3[3];
    #pragma unroll
    for (int j = 0; j < 3; ++j) acc3[j] = (f32x4){0.f,0.f,0.f,0.f};
    #pragma unroll
    for (int j = 0; j < 3; ++j)
        #pragma unroll
        for (int k = 0; k < KS; ++k) {
            short8 bf_ = *(const short8*)&bl[(j * 16 + m) * P + k * 32 + q * 8];
            acc3[j] = __builtin_amdgcn_mfma_f32_16x16x32_bf16(af4[k], bf_, acc3[j], 0, 0, 0);
        }

    __syncthreads();
    constexpr int CW3 = 49;
    #pragma unroll
    for (int j = 0; j < 3; ++j)
        #pragma unroll
        for (int r = 0; r < 4; ++r)
            accL[(wave * 16 + q * 4 + r) * CW3 + j * 16 + m] = acc3[j][r];
    __syncthreads();

    // fused log_softmax over 40 cols
    float mrow = 0.f, lrow = 0.f;
    if (lane < 16) {
        const float* rp = &accL[(wave * 16 + lane) * CW3];
        float mx = -1e30f;
        for (int c = 0; c < 40; ++c) mx = fmaxf(mx, rp[c] + bfc[c]);
        float s = 0.f;
        for (int c = 0; c < 40; ++c) s += expf(rp[c] + bfc[c] - mx);
        mrow = mx; lrow = logf(s);
    }
    for (int rl = 0; rl < 16; ++rl) {
        float mm = __shfl(mrow, rl);
        float ll = __shfl(lrow, rl);
        int rowD = rowbase + rl;
        if (rowD < M && lane < 40) {
            float v = accL[(wave * 16 + rl) * CW3 + lane] + bfc[lane];
            outF[(long long)rowD * 40 + lane] = v - mm - ll;
        }
    }
}

extern "C" void kernel_launch(void* const* d_in, const int* in_sizes, int n_in,
                              void* d_out, int out_size, void* d_ws, size_t ws_size,
                              hipStream_t stream) {
    const float* x     = (const float*)d_in[0];
    const int*   ei    = (const int*)d_in[1];
    const float* w_hid = (const float*)d_in[2];
    const float* b_hid = (const float*)d_in[3];
    const float* W_a1  = (const float*)d_in[4];
    const float* gcn1  = (const float*)d_in[5];
    const float* b_a1  = (const float*)d_in[6];
    const float* w2    = (const float*)d_in[7];
    const float* b2    = (const float*)d_in[8];
    const float* W_a2  = (const float*)d_in[9];
    const float* gcn2  = (const float*)d_in[10];
    const float* b_a2  = (const float*)d_in[11];
    const float* wfc   = (const float*)d_in[12];
    const float* bfc   = (const float*)d_in[13];
    float* ws = (float*)d_ws;
    float* out = (float*)d_out;

    float* dinv   = ws + O_DINV;
    int*   degi   = (int*)(ws + O_DEGI);
    int*   rowptr = (int*)(ws + O_ROWPTR);
    int*   gcur   = (int*)(ws + O_GCUR);
    int2*  ecsr   = (int2*)(ws + O_ECSR);
    u16* whB  = (u16*)(ws + O_WHB);
    u16* g1tB = (u16*)(ws + O_G1TB);
    u16* aw1B = (u16*)(ws + O_AW1B);
    u16* w2B  = (u16*)(ws + O_W2B);
    u16* aw2B = (u16*)(ws + O_AW2B);
    u16* g2tB = (u16*)(ws + O_G2TB);
    u16* wfcB = (u16*)(ws + O_WFCB);
    u16* aggB = (u16*)(ws + O_AGGB);
    u16* hB0  = (u16*)(ws + O_HB0);
    u16* hB1  = (u16*)(ws + O_HB1);
    u16* s0   = (u16*)(ws + O_S0);
    u16* s1   = (u16*)(ws + O_S1);
    u16* part = (u16*)(ws + O_PART);
    u16* base16 = (u16*)(ws + O_BASE);

    prep_kernel<<<(84481 + 255) / 256, 256, 0, stream>>>(
        w_hid, W_a1, gcn1, w2, W_a2, gcn2, wfc, ws);

    const int gatherBlocks = (NNODE * 64 + 255) / 256;   // 12500 (wave per node)

    // h = leaky_relu(x @ w_hid^T + b_hid) -> hB0 (+fp8 shadow s0);
    // blocks >= NTILE build per-slice degree partials via LDS histograms
    mgemm<8, 8, 1, 0, 1><<<NTILE + GH, 256, 0, stream>>>(
        x, whB, b_hid, nullptr, hB0, s0, NNODE, 128, 128, ei, part);

    alloc_kernel<<<(NNODE + 255) / 256, 256, 0, stream>>>(
        part, dinv, degi, rowptr, base16, gcur);
    fill_kernel<<<GH * NPASS, 256, 0, stream>>>(ei, dinv, rowptr, base16, ecsr);

    // conv1 iter1
    gather_kernel<128><<<gatherBlocks, 256, 0, stream>>>(
        rowptr, degi, ecsr, dinv, (const u32*)s0, aggB);
    mgemm_conv<4, 8, 0><<<NTILE, 256, 0, stream>>>(
        hB0, aggB, aw1B, g1tB, b_a1, hB1, s1, nullptr, nullptr, NNODE);
    // conv1 iter2
    gather_kernel<128><<<gatherBlocks, 256, 0, stream>>>(
        rowptr, degi, ecsr, dinv, (const u32*)s1, aggB);
    mgemm_conv<4, 8, 0><<<NTILE, 256, 0, stream>>>(
        hB1, aggB, aw1B, g1tB, b_a1, hB0, s0, nullptr, nullptr, NNODE);
    // conv1 iter3 + fused h2 = leaky(leaky(h_new)@w2^T + b2) -> hB1 (+shadow s1)
    gather_kernel<128><<<gatherBlocks, 256, 0, stream>>>(
        rowptr, degi, ecsr, dinv, (const u32*)s0, aggB);
    mgemm_conv<4, 8, 1><<<NTILE, 256, 0, stream>>>(
        hB0, aggB, aw1B, g1tB, b_a1, hB1, s1, w2B, b2, NNODE);

    // conv2 + fc + log_softmax
    gather_kernel<64><<<gatherBlocks, 256, 0, stream>>>(
        rowptr, degi, ecsr, dinv, (const u32*)s1, aggB);
    conv2fc<<<NTILE, 256, 0, stream>>>(
        hB1, aggB, aw2B, g2tB, b_a2, wfcB, bfc, out, NNODE);
}

// Round 12
// 355.902 us; speedup vs baseline: 1.0766x; 1.0198x over previous
//
#include <hip/hip_runtime.h>
#include <hip/hip_bf16.h>
#include <math.h>

typedef unsigned short u16;
typedef unsigned int   u32;
using short8  = __attribute__((ext_vector_type(8))) short;
using f32x4   = __attribute__((ext_vector_type(4))) float;

static constexpr int NNODE = 50000;
static constexpr int NEDGE = 600000;
static constexpr float EPSC   = 0.1f;
static constexpr float GAMMAC = 0.1f;

static constexpr int NTILE = (NNODE + 63) / 64;    // 782 GEMM row-tiles
static constexpr int GH    = 128;                  // histogram slices
static constexpr int NRNG  = 12500;                // nodes per histogram pass
static constexpr int NWORD = NRNG / 2;             // 6250 packed u32 words
static constexpr int NPASS = 4;                    // 4 x 12500 = 50000

// ---- workspace layout (float-index offsets) ----
static constexpr long long O_DINV   = 0;                         // float 50000
static constexpr long long O_DEGI   = 50000;                     // int 50000
static constexpr long long O_ROWPTR = 100000;                    // int 50000
static constexpr long long O_GCUR   = 150004;                    // int 1
static constexpr long long O_ECSR   = 200260;                    // int2 600000
// bf16 weights
static constexpr long long O_WHB    = 1400260;                   // 32768 bf16
static constexpr long long O_G1TB   = O_WHB  + 16384;
static constexpr long long O_AW1B   = O_G1TB + 8192;
static constexpr long long O_W2B    = O_AW1B + 8192;
static constexpr long long O_AW2B   = O_W2B  + 4096;
static constexpr long long O_G2TB   = O_AW2B + 2048;
static constexpr long long O_WFCB   = O_G2TB + 2048;
// big buffers
static constexpr long long O_AGGB   = 3450004;                   // bf16 6.4M
static constexpr long long O_HB0    = O_AGGB + 3200000;          // bf16 6.4M
static constexpr long long O_HB1    = O_HB0  + 3200000;          // bf16 6.4M
static constexpr long long O_S0     = O_HB1  + 3200000;          // fp8 6.4M
static constexpr long long O_S1     = O_S0   + 1600000;          // fp8 6.4M
// CSR de-atomization scratch
static constexpr long long O_PART   = O_S1   + 1600000;          // u16 GH x 50000
static constexpr long long O_BASE   = O_PART + 3200000;          // u16 GH x 50000

__device__ __forceinline__ float bf2f(u16 u) {
    return __uint_as_float(((unsigned)u) << 16);
}
__device__ __forceinline__ u16 f2bf(float f) {
    unsigned u = __float_as_uint(f);
    return (u16)((u + 0x7FFFu + ((u >> 16) & 1u)) >> 16);
}
// fast tanh: (e^{2x}-1)/(e^{2x}+1), clamped
__device__ __forceinline__ float ftanh(float x) {
    float x2 = fminf(fmaxf(2.f * x, -30.f), 30.f);
    float e = __expf(x2);
    return (e - 1.f) * __builtin_amdgcn_rcpf(e + 1.f);
}
// fp8 e4m3 pack/decode
__device__ __forceinline__ u16 pk_fp8(float a, float b) {
    int pk = __builtin_amdgcn_cvt_pk_fp8_f32(a, b, 0, false);
    return (u16)(pk & 0xffff);
}
__device__ __forceinline__ void acc_fp8x4(float* a, u32 v, float w) {
    a[0] += __builtin_amdgcn_cvt_f32_fp8(v, 0) * w;
    a[1] += __builtin_amdgcn_cvt_f32_fp8(v, 1) * w;
    a[2] += __builtin_amdgcn_cvt_f32_fp8(v, 2) * w;
    a[3] += __builtin_amdgcn_cvt_f32_fp8(v, 3) * w;
}

// ---- weight prep + gcur zero ----
__global__ __launch_bounds__(256) void prep_kernel(
    const float* __restrict__ w_hid, const float* __restrict__ W_a1,
    const float* __restrict__ gcn1,  const float* __restrict__ w2,
    const float* __restrict__ W_a2,  const float* __restrict__ gcn2,
    const float* __restrict__ wfc,   float* __restrict__ ws)
{
    int j = blockIdx.x * 256 + threadIdx.x;
    if (j < 32768) { ((u16*)(ws+O_WHB))[j] = f2bf(w_hid[j]); return; } j -= 32768;
    if (j < 16384) { int r=j>>7, c=j&127; ((u16*)(ws+O_G1TB))[j] = f2bf(gcn1[c*128+r]); return; } j -= 16384;
    if (j < 16384) { int r=j>>7, c=j&127;
                     ((u16*)(ws+O_AW1B))[j] = f2bf(W_a1[r*128+c] - W_a1[c*128+r] - (r==c?GAMMAC:0.f));
                     return; } j -= 16384;
    if (j < 8192)  { ((u16*)(ws+O_W2B))[j] = f2bf(w2[j]); return; } j -= 8192;
    if (j < 4096)  { int r=j>>6, c=j&63;
                     ((u16*)(ws+O_AW2B))[j] = f2bf(W_a2[r*64+c] - W_a2[c*64+r] - (r==c?GAMMAC:0.f));
                     return; } j -= 4096;
    if (j < 4096)  { int r=j>>6, c=j&63; ((u16*)(ws+O_G2TB))[j] = f2bf(gcn2[c*64+r]); return; } j -= 4096;
    if (j < 2560)  { ((u16*)(ws+O_WFCB))[j] = f2bf(wfc[j]); return; } j -= 2560;
    if (j == 0)    { ((int*)(ws+O_GCUR))[0] = 0; }
}

// ---- alloc: sum partials -> degi/dinv/base16; rowptr via wave-scan (1 atomic/wave) ----
__global__ __launch_bounds__(256) void alloc_kernel(
    const u16* __restrict__ part, float* __restrict__ dinv,
    int* __restrict__ degi, int* __restrict__ rowptr,
    u16* __restrict__ base16, int* __restrict__ gcur)
{
    int i = blockIdx.x * 256 + threadIdx.x;
    int lane = threadIdx.x & 63;
    bool ok = i < NNODE;
    int deg = 0;
    if (ok) {
        int run = 0;
        #pragma unroll 4
        for (int g = 0; g < GH; ++g) {
            base16[(long long)g * NNODE + i] = (u16)run;
            run += part[(long long)g * NNODE + i];
        }
        deg = run;
        degi[i] = deg;
        dinv[i] = rsqrtf(1.0f + (float)deg);   // +1 self loop
    }
    // inclusive wave scan of deg; one global atomic per wave
    int run = deg;
    #pragma unroll
    for (int off = 1; off < 64; off <<= 1) {
        int v = __shfl_up(run, off);
        if (lane >= off) run += v;
    }
    int tot = __shfl(run, 63);
    int basep = 0;
    if (lane == 63) basep = atomicAdd(gcur, tot);
    basep = __shfl(basep, 63);
    if (ok) rowptr[i] = basep + run - deg;
}

// ---- fill: one (slice g, node-range pass) per block -> 512-way parallel ----
__global__ __launch_bounds__(256) void fill_kernel(
    const int* __restrict__ ei, const float* __restrict__ dinv,
    const int* __restrict__ rowptr, const u16* __restrict__ base16,
    int2* __restrict__ ecsr)
{
    __shared__ u32 cur[NWORD];
    const int g    = blockIdx.x >> 2;            // slice
    const int pass = blockIdx.x & 3;             // node range
    const long long e0 = (long long)g * NEDGE / GH;
    const long long e1 = (long long)(g + 1) * NEDGE / GH;
    const u16* bb = base16 + (long long)g * NNODE;
    const int nbase = pass * NRNG;
    for (int wi = threadIdx.x; wi < NWORD; wi += 256) cur[wi] = 0;
    __syncthreads();
    for (long long e = e0 + threadIdx.x; e < e1; e += 256) {
        int d = ei[NEDGE + e];
        int r = d - nbase;
        if ((unsigned)r < (unsigned)NRNG) {
            int s = ei[e];
            u32 old = atomicAdd(&cur[r >> 1], 1u << ((r & 1) * 16));
            int rank = (int)((old >> ((r & 1) * 16)) & 0xffffu);
            int slot = rowptr[d] + (int)bb[d] + rank;
            int2 v;
            v.x = s;
            v.y = __float_as_int(dinv[s]);       // dinv[d] applied in gather epilogue
            ecsr[slot] = v;
        }
    }
}

// ---- MFMA GEMM (single-B): x @ w_hid^T, EPI=1; blocks >= NTILE build deg partials ----
template<int KS, int NT, int AF32, int LOADACT, int EPI>
__global__ __launch_bounds__(256, 4) void mgemm(
    const void* __restrict__ Araw,
    const u16* __restrict__ Bt,
    const float* __restrict__ bias,
    float* __restrict__ outF,
    u16* __restrict__ outB,
    u16* __restrict__ outB8,
    int M, int Nn, int ldc,
    const int* __restrict__ ei,      // edge dst for deg partials (may be null)
    u16* __restrict__ partial)       // GH x NNODE u16 (may be null)
{
    constexpr int K    = KS * 32;
    constexpr int KCHU = (K > 128) ? 128 : K;
    constexpr int KC   = KCHU / 32;
    constexpr int NCH  = K / KCHU;
    constexpr int P    = KCHU + 8;
    constexpr int ROWS = NT * 16;
    constexpr int CW   = NT * 16 + 1;
    constexpr int BSZ  = ROWS * P * 2;
    constexpr int ASZ  = 64 * CW * 4;
    constexpr int SMEM = BSZ > ASZ ? BSZ : ASZ;   // 34816 >= 25000 hist bytes
    __shared__ __align__(16) char smem[SMEM];

    // deg-partial role: LDS histogram (u16 pair packed per u32), NO fabric atomics
    if (ei && blockIdx.x >= NTILE) {
        int g = blockIdx.x - NTILE;               // 0..GH-1
        u32* hist = (u32*)smem;
        const long long e0 = (long long)g * NEDGE / GH;
        const long long e1 = (long long)(g + 1) * NEDGE / GH;
        u16* part = partial + (long long)g * NNODE;
        for (int pass = 0; pass < NPASS; ++pass) {
            const int nbase = pass * NRNG;
            for (int wi = threadIdx.x; wi < NWORD; wi += 256) hist[wi] = 0;
            __syncthreads();
            for (long long e = e0 + threadIdx.x; e < e1; e += 256) {
                int d = ei[NEDGE + e];
                int r = d - nbase;
                if ((unsigned)r < (unsigned)NRNG)
                    atomicAdd(&hist[r >> 1], 1u << ((r & 1) * 16));
            }
            __syncthreads();
            for (int wi = threadIdx.x; wi < NWORD; wi += 256)
                *(u32*)&part[nbase + wi * 2] = hist[wi];
            __syncthreads();
        }
        return;
    }

    u16*   bl   = (u16*)smem;
    float* accL = (float*)smem;

    const int wave = threadIdx.x >> 6;
    const int lane = threadIdx.x & 63;
    const int m = lane & 15, q = lane >> 4;
    const int rowbase = blockIdx.x * 64 + wave * 16;
    const int row = rowbase + m;
    const bool rok = row < M;
    const short8 z8 = {0,0,0,0,0,0,0,0};

    short8 af[KS];
    if (AF32) {
        const float* apf = (const float*)Araw + (long long)row * K;
        #pragma unroll
        for (int k = 0; k < KS; ++k) {
            short8 t = z8;
            if (rok) {
                const float4* p = (const float4*)(apf + (k * 4 + q) * 8);
                float4 a = p[0], b = p[1];
                t[0]=(short)f2bf(a.x); t[1]=(short)f2bf(a.y); t[2]=(short)f2bf(a.z); t[3]=(short)f2bf(a.w);
                t[4]=(short)f2bf(b.x); t[5]=(short)f2bf(b.y); t[6]=(short)f2bf(b.z); t[7]=(short)f2bf(b.w);
            }
            af[k] = t;
        }
    } else {
        const short8* ap = (const short8*)((const u16*)Araw + (long long)row * K);
        #pragma unroll
        for (int k = 0; k < KS; ++k) af[k] = rok ? ap[k * 4 + q] : z8;
    }
    if (LOADACT) {
        #pragma unroll
        for (int k = 0; k < KS; ++k)
            #pragma unroll
            for (int e = 0; e < 8; ++e) {
                float f = bf2f((u16)af[k][e]);
                f = f > 0.f ? f : 0.01f * f;
                af[k][e] = (short)f2bf(f);
            }
    }

    f32x4 acc[NT];
    #pragma unroll
    for (int j = 0; j < NT; ++j) acc[j] = (f32x4){0.f,0.f,0.f,0.f};

    for (int ch = 0; ch < NCH; ++ch) {
        if (ch) __syncthreads();
        constexpr int CHUNKS = ROWS * (KCHU / 8);
        for (int t = threadIdx.x; t < CHUNKS; t += 256) {
            int r = t / (KCHU / 8), c = t - r * (KCHU / 8);
            short8 v = z8;
            if (r < Nn) v = *(const short8*)&Bt[(long long)r * K + ch * KCHU + c * 8];
            *(short8*)&bl[r * P + c * 8] = v;
        }
        __syncthreads();
        #pragma unroll
        for (int j = 0; j < NT; ++j) {
            #pragma unroll
            for (int k = 0; k < KC; ++k) {
                short8 bf_ = *(const short8*)&bl[(j * 16 + m) * P + k * 32 + q * 8];
                acc[j] = __builtin_amdgcn_mfma_f32_16x16x32_bf16(af[ch * KC + k], bf_, acc[j], 0, 0, 0);
            }
        }
    }

    __syncthreads();
    #pragma unroll
    for (int j = 0; j < NT; ++j)
        #pragma unroll
        for (int r = 0; r < 4; ++r)
            accL[(wave * 16 + q * 4 + r) * CW + j * 16 + m] = acc[j][r];
    __syncthreads();

    const int c0 = lane * 2;
    if (c0 < NT * 16) {
        float2 bv = {0.f, 0.f};
        if (bias) {
            if (c0 < Nn)     bv.x = bias[c0];
            if (c0 + 1 < Nn) bv.y = bias[c0 + 1];
        }
        #pragma unroll
        for (int rl = 0; rl < 16; ++rl) {
            int rowD = rowbase + rl;
            if (rowD >= M) continue;
            float2 v = *(const float2*)&accL[(wave * 16 + rl) * CW + c0];
            long long o = (long long)rowD * ldc + c0;
            v.x += bv.x; v.y += bv.y;
            if (EPI == 1) {
                v.x = v.x > 0.f ? v.x : 0.01f * v.x;
                v.y = v.y > 0.f ? v.y : 0.01f * v.y;
            }
            if (c0 + 1 < Nn) {
                if (outB) { ushort2 ob; ob.x = f2bf(v.x); ob.y = f2bf(v.y);
                            *(ushort2*)&outB[o] = ob; }
                if (outB8) outB8[o >> 1] = pk_fp8(v.x, v.y);
                if (outF) { *(float2*)&outF[o] = v; }
            } else if (c0 < Nn) {
                if (outB) outB[o] = f2bf(v.x);
                if (outF) outF[o] = v.x;
            }
        }
    }
}

// ---- CSR gather (fp8 in, bf16 out), wave per node, dinv-hoisted, 4-unrolled ----
template<int HD>
__global__ __launch_bounds__(256) void gather_kernel(
    const int* __restrict__ rowptr, const int* __restrict__ degi,
    const int2* __restrict__ ecsr, const float* __restrict__ dinv,
    const u32* __restrict__ g8, u16* __restrict__ aggB)
{
    int node = (blockIdx.x * 256 + threadIdx.x) >> 6;
    int lane = threadIdx.x & 63;
    if (node >= NNODE) return;
    const int qr = lane >> 4, l4 = lane & 15;
    const int r0 = rowptr[node];
    const int r1 = r0 + degi[node];
    const float dn = dinv[node];
    constexpr int EL = (HD == 128) ? 8 : 4;

    float a[EL];
    #pragma unroll
    for (int i = 0; i < EL; ++i) a[i] = 0.f;
    if (qr == 0) {
        if (HD == 128) {
            uint2 gv = ((const uint2*)g8)[(long long)node * 16 + l4];
            acc_fp8x4(a, gv.x, dn);
            acc_fp8x4(a + 4, gv.y, dn);
        } else {
            u32 gv = g8[(long long)node * 16 + l4];
            acc_fp8x4(a, gv, dn);
        }
    }

    for (int base = r0; base < r1; base += 64) {
        int idx = base + lane;
        int cs = 0; float cw = 0.f;
        if (idx < r1) { int2 ev = ecsr[idx]; cs = ev.x; cw = __int_as_float(ev.y); }
        int cnt = min(64, r1 - base);
        for (int j = 0; j < cnt; j += 16) {
            #pragma unroll
            for (int u = 0; u < 4; ++u) {
                int jj = j + u * 4 + qr;
                int   s = __shfl(cs, jj);
                float w = __shfl(cw, jj);
                if (HD == 128) {
                    uint2 gv = ((const uint2*)g8)[(long long)s * 16 + l4];
                    acc_fp8x4(a, gv.x, w);
                    acc_fp8x4(a + 4, gv.y, w);
                } else {
                    u32 gv = g8[(long long)s * 16 + l4];
                    acc_fp8x4(a, gv, w);
                }
            }
        }
    }

    #pragma unroll
    for (int i = 0; i < EL; ++i) {
        a[i] += __shfl_xor(a[i], 16);
        a[i] += __shfl_xor(a[i], 32);
    }
    if (HD == 128) {
        float v0 = (qr == 0) ? a[0] : (qr == 1) ? a[2] : (qr == 2) ? a[4] : a[6];
        float v1 = (qr == 0) ? a[1] : (qr == 1) ? a[3] : (qr == 2) ? a[5] : a[7];
        v0 *= dn; v1 *= dn;
        long long o = (long long)node * 128 + l4 * 8 + qr * 2;
        ushort2 ob; ob.x = f2bf(v0); ob.y = f2bf(v1);
        *(ushort2*)&aggB[o] = ob;
    } else {
        float v = (qr == 0) ? a[0] : (qr == 1) ? a[1] : (qr == 2) ? a[2] : a[3];
        aggB[(long long)node * 64 + l4 * 4 + qr] = f2bf(v * dn);
    }
}

// ---- FUSED gather+conv (A/B experiment, iter1 only): 512 threads, 8 waves ----
// Gather phase: wave w gathers rows w*8..w*8+7 into LDS (24 waves/CU at 3 blk/CU,
// 4-unrolled ILP — fixes round-1's 12-wave serial-16 failure mode).
// Conv phase: r8-verified 512-thread dual-GEMM (B staged once, 4 row-quarters x 2 col-halves).
__global__ __launch_bounds__(512, 3) void fconv(
    const u16* __restrict__ hA, const u32* __restrict__ g8,
    const int* __restrict__ rowptr, const int* __restrict__ degi,
    const int2* __restrict__ ecsr, const float* __restrict__ dinv,
    const u16* __restrict__ BtW, const u16* __restrict__ BtG,
    const float* __restrict__ bias,
    u16* __restrict__ outB, u16* __restrict__ outB8)
{
    constexpr int K = 128, P = 136;
    __shared__ __align__(16) char smem[52224];
    u16* bl   = (u16*)smem;              // [128][136] B tile / accW epilogue
    u16* aggT = (u16*)(smem + 34816);    // [64][136] gathered rows
    const int wave = threadIdx.x >> 6, lane = threadIdx.x & 63;
    const int m = lane & 15, q = lane >> 4;
    const int blockrow = blockIdx.x * 64;
    const short8 z8 = {0,0,0,0,0,0,0,0};

    // ---- gather phase: 8 nodes per wave ----
    {
        const int qr = q, l4 = m;
        for (int nn = 0; nn < 8; ++nn) {
            int lr = wave * 8 + nn;
            int node = blockrow + lr;
            if (node >= NNODE) break;
            const int r0 = rowptr[node];
            const int r1 = r0 + degi[node];
            const float dn = dinv[node];
            float a[8] = {0.f,0.f,0.f,0.f,0.f,0.f,0.f,0.f};
            if (qr == 0) {
                uint2 gv = ((const uint2*)g8)[(long long)node * 16 + l4];
                acc_fp8x4(a, gv.x, dn);
                acc_fp8x4(a + 4, gv.y, dn);
            }
            for (int base = r0; base < r1; base += 64) {
                int idx = base + lane;
                int cs = 0; float cw = 0.f;
                if (idx < r1) { int2 ev = ecsr[idx]; cs = ev.x; cw = __int_as_float(ev.y); }
                int cnt = min(64, r1 - base);
                for (int j = 0; j < cnt; j += 16) {
                    #pragma unroll
                    for (int u = 0; u < 4; ++u) {
                        int jj = j + u * 4 + qr;
                        int   s = __shfl(cs, jj);
                        float w = __shfl(cw, jj);
                        uint2 gv = ((const uint2*)g8)[(long long)s * 16 + l4];
                        acc_fp8x4(a, gv.x, w);
                        acc_fp8x4(a + 4, gv.y, w);
                    }
                }
            }
            #pragma unroll
            for (int i = 0; i < 8; ++i) {
                a[i] += __shfl_xor(a[i], 16);
                a[i] += __shfl_xor(a[i], 32);
            }
            float v0 = (qr == 0) ? a[0] : (qr == 1) ? a[2] : (qr == 2) ? a[4] : a[6];
            float v1 = (qr == 0) ? a[1] : (qr == 1) ? a[3] : (qr == 2) ? a[5] : a[7];
            v0 *= dn; v1 *= dn;
            ushort2 ob; ob.x = f2bf(v0); ob.y = f2bf(v1);
            *(ushort2*)&aggT[lr * P + l4 * 8 + qr * 2] = ob;
        }
    }
    __syncthreads();      // aggT complete for all 64 rows

    // ---- conv phase (r8 convs structure) ----
    const int nh = wave >> 2;                 // col-half
    const int rowbase = blockrow + (wave & 3) * 16;
    const int row = rowbase + m;
    const bool rok = row < NNODE;

    short8 af1[4], af2[4];
    {
        const short8* ap1 = (const short8*)(hA + (long long)row * K);
        #pragma unroll
        for (int k = 0; k < 4; ++k) {
            af1[k] = rok ? ap1[k * 4 + q] : z8;
            af2[k] = rok ? *(const short8*)&aggT[((wave & 3) * 16 + m) * P + k * 32 + q * 8] : z8;
        }
    }

    f32x4 acc[4];
    #pragma unroll
    for (int j = 0; j < 4; ++j) acc[j] = (f32x4){0.f,0.f,0.f,0.f};

    #pragma unroll
    for (int pass = 0; pass < 2; ++pass) {    // W then G, full [128][136] staged
        const u16* Bsrc = pass ? BtG : BtW;
        if (pass) __syncthreads();
        for (int t = threadIdx.x; t < 2048; t += 512) {
            int r = t >> 4, c = t & 15;
            *(short8*)&bl[r * P + c * 8] = *(const short8*)&Bsrc[(long long)r * K + c * 8];
        }
        __syncthreads();
        #pragma unroll
        for (int j = 0; j < 4; ++j)
            #pragma unroll
            for (int kk = 0; kk < 4; ++kk) {
                short8 b_ = *(const short8*)&bl[(nh*64 + j*16 + m) * P + kk*32 + q*8];
                acc[j] = __builtin_amdgcn_mfma_f32_16x16x32_bf16(
                    pass ? af2[kk] : af1[kk], b_, acc[j], 0, 0, 0);
            }
    }

    __syncthreads();
    float* accW = (float*)smem + wave * 16 * 65;   // 8 waves x 4160B = 33280 <= 52224
    #pragma unroll
    for (int j = 0; j < 4; ++j)
        #pragma unroll
        for (int r = 0; r < 4; ++r)
            accW[(q*4 + r) * 65 + j*16 + m] = acc[j][r];

    const int hw = lane >> 5;
    const int c0 = (lane & 31) * 2;
    float2 bv = {bias[nh*64 + c0], bias[nh*64 + c0 + 1]};
    #pragma unroll
    for (int rl8 = 0; rl8 < 8; ++rl8) {
        int rl = hw * 8 + rl8;
        int rowD = rowbase + rl;
        if (rowD >= NNODE) continue;
        float2 v = *(const float2*)&accW[rl * 65 + c0];
        long long o = (long long)rowD * 128 + nh*64 + c0;
        ushort2 hh = *(const ushort2*)&hA[o];
        float n0 = bf2f(hh.x) + EPSC * ftanh(v.x + bv.x);
        float n1 = bf2f(hh.y) + EPSC * ftanh(v.y + bv.y);
        ushort2 ob; ob.x = f2bf(n0); ob.y = f2bf(n1);
        *(ushort2*)&outB[o] = ob;
        outB8[o >> 1] = pk_fp8(n0, n1);
    }
}

// ---- conv-step GEMM: acc = h@aW^T + (Âh)@G, epi h+eps*tanh(acc+b) ----
// TAIL=0: write h_new (bf16) + fp8 shadow.
// TAIL=1: additionally fuse h2 = leaky(leaky(h_new)@w2^T + b2).
//         SLIM: register-hv epilogue (r3/r4-verified) -> LDS 34816, 4 blocks/CU.
template<int KS, int NT, int TAIL>
__global__ __launch_bounds__(256, 4) void mgemm_conv(
    const u16* __restrict__ hA,      // h  [M,K] bf16
    const u16* __restrict__ gA,      // Âh [M,K] bf16
    const u16* __restrict__ BtW,
    const u16* __restrict__ BtG,
    const float* __restrict__ bias,
    u16* __restrict__ outB,
    u16* __restrict__ outB8,         // fp8 shadow of output, may be null
    const u16* __restrict__ w2W,     // TAIL only: w2 [64,128] bf16
    const float* __restrict__ b2,    // TAIL only
    int M)
{
    constexpr int K    = KS * 32;
    constexpr int Nn   = NT * 16;
    constexpr int P    = K + 8;
    constexpr int CW   = Nn + 1;
    constexpr int BSZ  = Nn * P * 2;
    constexpr int ASZ  = 64 * CW * 4;
    constexpr int R1   = BSZ > ASZ ? BSZ : ASZ;   // 34816 for KS=4,NT=8
    __shared__ __align__(16) char smem[R1];
    u16*   bl   = (u16*)smem;
    float* accL = (float*)smem;

    const int wave = threadIdx.x >> 6;
    const int lane = threadIdx.x & 63;
    const int m = lane & 15, q = lane >> 4;
    const int rowbase = blockIdx.x * 64 + wave * 16;
    const int row = rowbase + m;
    const bool rok = row < M;
    const short8 z8 = {0,0,0,0,0,0,0,0};

    short8 af1[KS], af2[KS];
    {
        const short8* ap1 = (const short8*)(hA + (long long)row * K);
        const short8* ap2 = (const short8*)(gA + (long long)row * K);
        #pragma unroll
        for (int k = 0; k < KS; ++k) {
            af1[k] = rok ? ap1[k * 4 + q] : z8;
            af2[k] = rok ? ap2[k * 4 + q] : z8;
        }
    }

    f32x4 acc[NT];
    #pragma unroll
    for (int j = 0; j < NT; ++j) acc[j] = (f32x4){0.f,0.f,0.f,0.f};

    #pragma unroll
    for (int pass = 0; pass < 2; ++pass) {
        const u16* Bcur = pass ? BtG : BtW;
        if (pass) __syncthreads();
        constexpr int CHUNKS = Nn * (K / 8);
        for (int t = threadIdx.x; t < CHUNKS; t += 256) {
            int r = t / (K / 8), c = t - r * (K / 8);
            *(short8*)&bl[r * P + c * 8] = *(const short8*)&Bcur[(long long)r * K + c * 8];
        }
        __syncthreads();
        #pragma unroll
        for (int j = 0; j < NT; ++j) {
            #pragma unroll
            for (int k = 0; k < KS; ++k) {
                short8 bf_ = *(const short8*)&bl[(j * 16 + m) * P + k * 32 + q * 8];
                acc[j] = __builtin_amdgcn_mfma_f32_16x16x32_bf16(
                    pass ? af2[k] : af1[k], bf_, acc[j], 0, 0, 0);
            }
        }
    }

    __syncthreads();
    #pragma unroll
    for (int j = 0; j < NT; ++j)
        #pragma unroll
        for (int r = 0; r < 4; ++r)
            accL[(wave * 16 + q * 4 + r) * CW + j * 16 + m] = acc[j][r];
    __syncthreads();

    const int c0 = lane * 2;
    if (TAIL == 0) {
        if (c0 < Nn) {
            float2 bv = {bias[c0], bias[c0 + 1]};
            #pragma unroll
            for (int rl = 0; rl < 16; ++rl) {
                int rowD = rowbase + rl;
                if (rowD >= M) continue;
                float2 v = *(const float2*)&accL[(wave * 16 + rl) * CW + c0];
                long long o = (long long)rowD * Nn + c0;
                ushort2 hh = *(const ushort2*)&hA[o];
                float n0 = bf2f(hh.x) + EPSC * ftanh(v.x + bv.x);
                float n1 = bf2f(hh.y) + EPSC * ftanh(v.y + bv.y);
                ushort2 ob; ob.x = f2bf(n0); ob.y = f2bf(n1);
                *(ushort2*)&outB[o] = ob;
                if (outB8) outB8[o >> 1] = pk_fp8(n0, n1);
            }
        }
        return;
    }

    // ---- TAIL=1 SLIM: leaky(h_new) -> hv regs, repurpose smem (r3/r4 pattern) ----
    u32 hv[16];
    {
        float2 bv = {bias[c0], bias[c0 + 1]};
        #pragma unroll
        for (int rl = 0; rl < 16; ++rl) {
            int rowD = rowbase + rl;
            float n0 = 0.f, n1 = 0.f;
            if (rowD < M) {
                float2 v = *(const float2*)&accL[(wave * 16 + rl) * CW + c0];
                long long o = (long long)rowD * K + c0;
                ushort2 hh = *(const ushort2*)&hA[o];
                n0 = bf2f(hh.x) + EPSC * ftanh(v.x + bv.x);
                n1 = bf2f(hh.y) + EPSC * ftanh(v.y + bv.y);
                n0 = n0 > 0.f ? n0 : 0.01f * n0;
                n1 = n1 > 0.f ? n1 : 0.01f * n1;
            }
            hv[rl] = (u32)f2bf(n0) | ((u32)f2bf(n1) << 16);
        }
    }
    __syncthreads();   // everyone done reading accL; smem repurposed

    u16* aggT = (u16*)smem;            // [64][136] bf16, 17408 B
    u16* bl2  = (u16*)(smem + 17408);  // w2 [64][136] bf16, 17408 B
    #pragma unroll
    for (int rl = 0; rl < 16; ++rl)
        *(u32*)&aggT[(wave * 16 + rl) * P + c0] = hv[rl];
    for (int t = threadIdx.x; t < 1024; t += 256) {
        int r = t >> 4, c = t & 15;
        *(short8*)&bl2[r * P + c * 8] = *(const short8*)&w2W[(long long)r * K + c * 8];
    }
    __syncthreads();

    short8 af3[4];
    #pragma unroll
    for (int k = 0; k < 4; ++k)
        af3[k] = *(const short8*)&aggT[(wave * 16 + m) * P + k * 32 + q * 8];

    f32x4 acc2[4];
    #pragma unroll
    for (int j = 0; j < 4; ++j) acc2[j] = (f32x4){0.f,0.f,0.f,0.f};
    #pragma unroll
    for (int j = 0; j < 4; ++j)
        #pragma unroll
        for (int k = 0; k < 4; ++k) {
            short8 bf_ = *(const short8*)&bl2[(j * 16 + m) * P + k * 32 + q * 8];
            acc2[j] = __builtin_amdgcn_mfma_f32_16x16x32_bf16(af3[k], bf_, acc2[j], 0, 0, 0);
        }

    __syncthreads();
    constexpr int CW2 = 65;
    float* accL2 = (float*)smem;       // 16640 B, overwrites aggT (af3 in regs)
    #pragma unroll
    for (int j = 0; j < 4; ++j)
        #pragma unroll
        for (int r = 0; r < 4; ++r)
            accL2[(wave * 16 + q * 4 + r) * CW2 + j * 16 + m] = acc2[j][r];
    __syncthreads();

    if (c0 < 64) {
        float2 bv = {b2[c0], b2[c0 + 1]};
        #pragma unroll
        for (int rl = 0; rl < 16; ++rl) {
            int rowD = rowbase + rl;
            if (rowD >= M) continue;
            float2 v = *(const float2*)&accL2[(wave * 16 + rl) * CW2 + c0];
            v.x += bv.x; v.y += bv.y;
            v.x = v.x > 0.f ? v.x : 0.01f * v.x;
            v.y = v.y > 0.f ? v.y : 0.01f * v.y;
            long long o = (long long)rowD * 64 + c0;
            ushort2 ob; ob.x = f2bf(v.x); ob.y = f2bf(v.y);
            *(ushort2*)&outB[o] = ob;
            outB8[o >> 1] = pk_fp8(v.x, v.y);
        }
    }
}

// ---- fused conv2 + FC + log_softmax (agg from global) ----
__global__ __launch_bounds__(256, 4) void conv2fc(
    const u16* __restrict__ hA,      // h2 [M,64] bf16
    const u16* __restrict__ gA,      // Âh2 [M,64] bf16 (from gather<64>)
    const u16* __restrict__ BtW, const u16* __restrict__ BtG,
    const float* __restrict__ bias,
    const u16* __restrict__ wfcB, const float* __restrict__ bfc,
    float* __restrict__ outF, int M)
{
    constexpr int K  = 64, NT = 4, KS = 2;
    constexpr int P  = K + 8;                 // 72
    constexpr int CW = 65;
    constexpr int R1 = 64 * CW * 4;           // 16640
    __shared__ __align__(16) char smem[R1 + 64 * P * 2];
    u16*   bl   = (u16*)smem;
    float* accL = (float*)smem;
    u16*   aggT = (u16*)(smem + R1);

    const int wave = threadIdx.x >> 6;
    const int lane = threadIdx.x & 63;
    const int m = lane & 15, q = lane >> 4;
    const int rowbase = blockIdx.x * 64 + wave * 16;
    const int row = rowbase + m;
    const bool rok = row < M;
    const short8 z8 = {0,0,0,0,0,0,0,0};

    short8 af1[KS], af2[KS];
    {
        const short8* ap1 = (const short8*)(hA + (long long)row * K);
        const short8* ap2 = (const short8*)(gA + (long long)row * K);
        #pragma unroll
        for (int k = 0; k < KS; ++k) {
            af1[k] = rok ? ap1[k * 4 + q] : z8;
            af2[k] = rok ? ap2[k * 4 + q] : z8;
        }
    }

    f32x4 acc[NT];
    #pragma unroll
    for (int j = 0; j < NT; ++j) acc[j] = (f32x4){0.f,0.f,0.f,0.f};

    #pragma unroll
    for (int pass = 0; pass < 2; ++pass) {
        const u16* Bcur = pass ? BtG : BtW;
        if (pass) __syncthreads();
        constexpr int CHUNKS = 64 * (K / 8);      // 512
        for (int t = threadIdx.x; t < CHUNKS; t += 256) {
            int r = t >> 3, c = t & 7;
            *(short8*)&bl[r * P + c * 8] = *(const short8*)&Bcur[(long long)r * K + c * 8];
        }
        __syncthreads();
        #pragma unroll
        for (int j = 0; j < NT; ++j)
            #pragma unroll
            for (int k = 0; k < KS; ++k) {
                short8 bf_ = *(const short8*)&bl[(j * 16 + m) * P + k * 32 + q * 8];
                acc[j] = __builtin_amdgcn_mfma_f32_16x16x32_bf16(
                    pass ? af2[k] : af1[k], bf_, acc[j], 0, 0, 0);
            }
    }

    __syncthreads();
    #pragma unroll
    for (int j = 0; j < NT; ++j)
        #pragma unroll
        for (int r = 0; r < 4; ++r)
            accL[(wave * 16 + q * 4 + r) * CW + j * 16 + m] = acc[j][r];
    __syncthreads();

    // epilogue1: h2n = h2 + eps*tanh(acc + b_a2) -> aggT tile
    {
        const int c0 = lane * 2;
        float2 bv = {bias[c0 & 63], bias[(c0 + 1) & 63]};
        if (c0 < 64) {
            #pragma unroll
            for (int rl = 0; rl < 16; ++rl) {
                int rowD = rowbase + rl;
                float n0 = 0.f, n1 = 0.f;
                if (rowD < M) {
                    float2 v = *(const float2*)&accL[(wave * 16 + rl) * CW + c0];
                    long long o = (long long)rowD * 64 + c0;
                    ushort2 hh = *(const ushort2*)&hA[o];
                    n0 = bf2f(hh.x) + EPSC * ftanh(v.x + bv.x);
                    n1 = bf2f(hh.y) + EPSC * ftanh(v.y + bv.y);
                }
                ushort2 ob; ob.x = f2bf(n0); ob.y = f2bf(n1);
                *(ushort2*)&aggT[(wave * 16 + rl) * P + c0] = ob;
            }
        }
    }
    __syncthreads();   // accL region about to be restaged with wfc

    short8 af4[KS];
    #pragma unroll
    for (int k = 0; k < KS; ++k)
        af4[k] = *(const short8*)&aggT[(wave * 16 + m) * P + k * 32 + q * 8];

    // stage wfc [40,64], zero-pad rows 40..47 (NT=3 -> 48 rows)
    {
        constexpr int CHF = 48 * 8;
        for (int t = threadIdx.x; t < CHF; t += 256) {
            int r = t >> 3, c = t & 7;
            short8 v = z8;
            if (r < 40) v = *(const short8*)&wfcB[(long long)r * K + c * 8];
            *(short8*)&bl[r * P + c * 8] = v;
        }
    }
    __syncthreads();

    f32x4 acc3[3];
    #pragma unroll
    for (int j = 0; j < 3; ++j) acc3[j] = (f32x4){0.f,0.f,0.f,0.f};
    #pragma unroll
    for (int j = 0; j < 3; ++j)
        #pragma unroll
        for (int k = 0; k < KS; ++k) {
            short8 bf_ = *(const short8*)&bl[(j * 16 + m) * P + k * 32 + q * 8];
            acc3[j] = __builtin_amdgcn_mfma_f32_16x16x32_bf16(af4[k], bf_, acc3[j], 0, 0, 0);
        }

    __syncthreads();
    constexpr int CW3 = 49;
    #pragma unroll
    for (int j = 0; j < 3; ++j)
        #pragma unroll
        for (int r = 0; r < 4; ++r)
            accL[(wave * 16 + q * 4 + r) * CW3 + j * 16 + m] = acc3[j][r];
    __syncthreads();

    // fused log_softmax over 40 cols
    float mrow = 0.f, lrow = 0.f;
    if (lane < 16) {
        const float* rp = &accL[(wave * 16 + lane) * CW3];
        float mx = -1e30f;
        for (int c = 0; c < 40; ++c) mx = fmaxf(mx, rp[c] + bfc[c]);
        float s = 0.f;
        for (int c = 0; c < 40; ++c) s += expf(rp[c] + bfc[c] - mx);
        mrow = mx; lrow = logf(s);
    }
    for (int rl = 0; rl < 16; ++rl) {
        float mm = __shfl(mrow, rl);
        float ll = __shfl(lrow, rl);
        int rowD = rowbase + rl;
        if (rowD < M && lane < 40) {
            float v = accL[(wave * 16 + rl) * CW3 + lane] + bfc[lane];
            outF[(long long)rowD * 40 + lane] = v - mm - ll;
        }
    }
}

extern "C" void kernel_launch(void* const* d_in, const int* in_sizes, int n_in,
                              void* d_out, int out_size, void* d_ws, size_t ws_size,
                              hipStream_t stream) {
    const float* x     = (const float*)d_in[0];
    const int*   ei    = (const int*)d_in[1];
    const float* w_hid = (const float*)d_in[2];
    const float* b_hid = (const float*)d_in[3];
    const float* W_a1  = (const float*)d_in[4];
    const float* gcn1  = (const float*)d_in[5];
    const float* b_a1  = (const float*)d_in[6];
    const float* w2    = (const float*)d_in[7];
    const float* b2    = (const float*)d_in[8];
    const float* W_a2  = (const float*)d_in[9];
    const float* gcn2  = (const float*)d_in[10];
    const float* b_a2  = (const float*)d_in[11];
    const float* wfc   = (const float*)d_in[12];
    const float* bfc   = (const float*)d_in[13];
    float* ws = (float*)d_ws;
    float* out = (float*)d_out;

    float* dinv   = ws + O_DINV;
    int*   degi   = (int*)(ws + O_DEGI);
    int*   rowptr = (int*)(ws + O_ROWPTR);
    int*   gcur   = (int*)(ws + O_GCUR);
    int2*  ecsr   = (int2*)(ws + O_ECSR);
    u16* whB  = (u16*)(ws + O_WHB);
    u16* g1tB = (u16*)(ws + O_G1TB);
    u16* aw1B = (u16*)(ws + O_AW1B);
    u16* w2B  = (u16*)(ws + O_W2B);
    u16* aw2B = (u16*)(ws + O_AW2B);
    u16* g2tB = (u16*)(ws + O_G2TB);
    u16* wfcB = (u16*)(ws + O_WFCB);
    u16* aggB = (u16*)(ws + O_AGGB);
    u16* hB0  = (u16*)(ws + O_HB0);
    u16* hB1  = (u16*)(ws + O_HB1);
    u16* s0   = (u16*)(ws + O_S0);
    u16* s1   = (u16*)(ws + O_S1);
    u16* part = (u16*)(ws + O_PART);
    u16* base16 = (u16*)(ws + O_BASE);

    prep_kernel<<<(84481 + 255) / 256, 256, 0, stream>>>(
        w_hid, W_a1, gcn1, w2, W_a2, gcn2, wfc, ws);

    const int gatherBlocks = (NNODE * 64 + 255) / 256;   // 12500 (wave per node)

    // h = leaky_relu(x @ w_hid^T + b_hid) -> hB0 (+fp8 shadow s0);
    // blocks >= NTILE build per-slice degree partials via LDS histograms
    mgemm<8, 8, 1, 0, 1><<<NTILE + GH, 256, 0, stream>>>(
        x, whB, b_hid, nullptr, hB0, s0, NNODE, 128, 128, ei, part);

    alloc_kernel<<<(NNODE + 255) / 256, 256, 0, stream>>>(
        part, dinv, degi, rowptr, base16, gcur);
    fill_kernel<<<GH * NPASS, 256, 0, stream>>>(ei, dinv, rowptr, base16, ecsr);

    // conv1 iter1: FUSED gather+conv (A/B experiment vs split iter2/3)
    fconv<<<NTILE, 512, 0, stream>>>(hB0, (const u32*)s0, rowptr, degi, ecsr, dinv,
                                     aw1B, g1tB, b_a1, hB1, s1);
    // conv1 iter2 (split, as before)
    gather_kernel<128><<<gatherBlocks, 256, 0, stream>>>(
        rowptr, degi, ecsr, dinv, (const u32*)s1, aggB);
    mgemm_conv<4, 8, 0><<<NTILE, 256, 0, stream>>>(
        hB1, aggB, aw1B, g1tB, b_a1, hB0, s0, nullptr, nullptr, NNODE);
    // conv1 iter3 + fused h2 = leaky(leaky(h_new)@w2^T + b2) -> hB1 (+shadow s1)
    gather_kernel<128><<<gatherBlocks, 256, 0, stream>>>(
        rowptr, degi, ecsr, dinv, (const u32*)s0, aggB);
    mgemm_conv<4, 8, 1><<<NTILE, 256, 0, stream>>>(
        hB0, aggB, aw1B, g1tB, b_a1, hB1, s1, w2B, b2, NNODE);

    // conv2 + fc + log_softmax
    gather_kernel<64><<<gatherBlocks, 256, 0, stream>>>(
        rowptr, degi, ecsr, dinv, (const u32*)s1, aggB);
    conv2fc<<<NTILE, 256, 0, stream>>>(
        hB1, aggB, aw2B, g2tB, b_a2, wfcB, bfc, out, NNODE);
}

// Round 13
// 355.412 us; speedup vs baseline: 1.0781x; 1.0014x over previous
//
#include <hip/hip_runtime.h>
#include <hip/hip_bf16.h>
#include <math.h>

typedef unsigned short u16;
typedef unsigned int   u32;
using short8  = __attribute__((ext_vector_type(8))) short;
using f32x4   = __attribute__((ext_vector_type(4))) float;

static constexpr int NNODE = 50000;
static constexpr int NEDGE = 600000;
static constexpr float EPSC   = 0.1f;
static constexpr float GAMMAC = 0.1f;

static constexpr int NTILE = (NNODE + 63) / 64;    // 782 GEMM row-tiles
static constexpr int GH    = 128;                  // histogram slices
static constexpr int NRNG  = 12500;                // nodes per histogram pass
static constexpr int NWORD = NRNG / 2;             // 6250 packed u32 words
static constexpr int NPASS = 4;                    // 4 x 12500 = 50000

// ---- workspace layout (float-index offsets) ----
static constexpr long long O_DINV   = 0;                         // float 50000
static constexpr long long O_DEGI   = 50000;                     // int 50000
static constexpr long long O_ROWPTR = 100000;                    // int 50000
static constexpr long long O_GCUR   = 150004;                    // int 1
static constexpr long long O_ECSR   = 200260;                    // int2 600000
// bf16 weights
static constexpr long long O_WHB    = 1400260;                   // 32768 bf16
static constexpr long long O_G1TB   = O_WHB  + 16384;
static constexpr long long O_AW1B   = O_G1TB + 8192;
static constexpr long long O_W2B    = O_AW1B + 8192;
static constexpr long long O_AW2B   = O_W2B  + 4096;
static constexpr long long O_G2TB   = O_AW2B + 2048;
static constexpr long long O_WFCB   = O_G2TB + 2048;
// big buffers
static constexpr long long O_AGGB   = 3450004;                   // bf16 6.4M
static constexpr long long O_HB0    = O_AGGB + 3200000;          // bf16 6.4M
static constexpr long long O_HB1    = O_HB0  + 3200000;          // bf16 6.4M
static constexpr long long O_S0     = O_HB1  + 3200000;          // fp8 6.4M
static constexpr long long O_S1     = O_S0   + 1600000;          // fp8 6.4M
// CSR de-atomization scratch
static constexpr long long O_PART   = O_S1   + 1600000;          // u16 GH x 50000
static constexpr long long O_BASE   = O_PART + 3200000;          // u16 GH x 50000

__device__ __forceinline__ float bf2f(u16 u) {
    return __uint_as_float(((unsigned)u) << 16);
}
__device__ __forceinline__ u16 f2bf(float f) {
    unsigned u = __float_as_uint(f);
    return (u16)((u + 0x7FFFu + ((u >> 16) & 1u)) >> 16);
}
// fast tanh: (e^{2x}-1)/(e^{2x}+1), clamped
__device__ __forceinline__ float ftanh(float x) {
    float x2 = fminf(fmaxf(2.f * x, -30.f), 30.f);
    float e = __expf(x2);
    return (e - 1.f) * __builtin_amdgcn_rcpf(e + 1.f);
}
// fp8 e4m3 pack/decode
__device__ __forceinline__ u16 pk_fp8(float a, float b) {
    int pk = __builtin_amdgcn_cvt_pk_fp8_f32(a, b, 0, false);
    return (u16)(pk & 0xffff);
}
__device__ __forceinline__ void acc_fp8x4(float* a, u32 v, float w) {
    a[0] += __builtin_amdgcn_cvt_f32_fp8(v, 0) * w;
    a[1] += __builtin_amdgcn_cvt_f32_fp8(v, 1) * w;
    a[2] += __builtin_amdgcn_cvt_f32_fp8(v, 2) * w;
    a[3] += __builtin_amdgcn_cvt_f32_fp8(v, 3) * w;
}

// ---- weight prep + gcur zero ----
__global__ __launch_bounds__(256) void prep_kernel(
    const float* __restrict__ w_hid, const float* __restrict__ W_a1,
    const float* __restrict__ gcn1,  const float* __restrict__ w2,
    const float* __restrict__ W_a2,  const float* __restrict__ gcn2,
    const float* __restrict__ wfc,   float* __restrict__ ws)
{
    int j = blockIdx.x * 256 + threadIdx.x;
    if (j < 32768) { ((u16*)(ws+O_WHB))[j] = f2bf(w_hid[j]); return; } j -= 32768;
    if (j < 16384) { int r=j>>7, c=j&127; ((u16*)(ws+O_G1TB))[j] = f2bf(gcn1[c*128+r]); return; } j -= 16384;
    if (j < 16384) { int r=j>>7, c=j&127;
                     ((u16*)(ws+O_AW1B))[j] = f2bf(W_a1[r*128+c] - W_a1[c*128+r] - (r==c?GAMMAC:0.f));
                     return; } j -= 16384;
    if (j < 8192)  { ((u16*)(ws+O_W2B))[j] = f2bf(w2[j]); return; } j -= 8192;
    if (j < 4096)  { int r=j>>6, c=j&63;
                     ((u16*)(ws+O_AW2B))[j] = f2bf(W_a2[r*64+c] - W_a2[c*64+r] - (r==c?GAMMAC:0.f));
                     return; } j -= 4096;
    if (j < 4096)  { int r=j>>6, c=j&63; ((u16*)(ws+O_G2TB))[j] = f2bf(gcn2[c*64+r]); return; } j -= 4096;
    if (j < 2560)  { ((u16*)(ws+O_WFCB))[j] = f2bf(wfc[j]); return; } j -= 2560;
    if (j == 0)    { ((int*)(ws+O_GCUR))[0] = 0; }
}

// ---- alloc: sum partials -> degi/dinv/base16; rowptr via wave-scan (1 atomic/wave) ----
__global__ __launch_bounds__(256) void alloc_kernel(
    const u16* __restrict__ part, float* __restrict__ dinv,
    int* __restrict__ degi, int* __restrict__ rowptr,
    u16* __restrict__ base16, int* __restrict__ gcur)
{
    int i = blockIdx.x * 256 + threadIdx.x;
    int lane = threadIdx.x & 63;
    bool ok = i < NNODE;
    int deg = 0;
    if (ok) {
        int run = 0;
        #pragma unroll 4
        for (int g = 0; g < GH; ++g) {
            base16[(long long)g * NNODE + i] = (u16)run;
            run += part[(long long)g * NNODE + i];
        }
        deg = run;
        degi[i] = deg;
        dinv[i] = rsqrtf(1.0f + (float)deg);   // +1 self loop
    }
    // inclusive wave scan of deg; one global atomic per wave
    int run = deg;
    #pragma unroll
    for (int off = 1; off < 64; off <<= 1) {
        int v = __shfl_up(run, off);
        if (lane >= off) run += v;
    }
    int tot = __shfl(run, 63);
    int basep = 0;
    if (lane == 63) basep = atomicAdd(gcur, tot);
    basep = __shfl(basep, 63);
    if (ok) rowptr[i] = basep + run - deg;
}

// ---- fill: one (slice g, node-range pass) per block -> 512-way parallel ----
__global__ __launch_bounds__(256) void fill_kernel(
    const int* __restrict__ ei, const float* __restrict__ dinv,
    const int* __restrict__ rowptr, const u16* __restrict__ base16,
    int2* __restrict__ ecsr)
{
    __shared__ u32 cur[NWORD];
    const int g    = blockIdx.x >> 2;            // slice
    const int pass = blockIdx.x & 3;             // node range
    const long long e0 = (long long)g * NEDGE / GH;
    const long long e1 = (long long)(g + 1) * NEDGE / GH;
    const u16* bb = base16 + (long long)g * NNODE;
    const int nbase = pass * NRNG;
    for (int wi = threadIdx.x; wi < NWORD; wi += 256) cur[wi] = 0;
    __syncthreads();
    for (long long e = e0 + threadIdx.x; e < e1; e += 256) {
        int d = ei[NEDGE + e];
        int r = d - nbase;
        if ((unsigned)r < (unsigned)NRNG) {
            int s = ei[e];
            u32 old = atomicAdd(&cur[r >> 1], 1u << ((r & 1) * 16));
            int rank = (int)((old >> ((r & 1) * 16)) & 0xffffu);
            int slot = rowptr[d] + (int)bb[d] + rank;
            int2 v;
            v.x = s;
            v.y = __float_as_int(dinv[s]);       // dinv[d] applied in gather epilogue
            ecsr[slot] = v;
        }
    }
}

// ---- MFMA GEMM (single-B): x @ w_hid^T, EPI=1; blocks >= NTILE build deg partials ----
template<int KS, int NT, int AF32, int LOADACT, int EPI>
__global__ __launch_bounds__(256, 4) void mgemm(
    const void* __restrict__ Araw,
    const u16* __restrict__ Bt,
    const float* __restrict__ bias,
    float* __restrict__ outF,
    u16* __restrict__ outB,
    u16* __restrict__ outB8,
    int M, int Nn, int ldc,
    const int* __restrict__ ei,      // edge dst for deg partials (may be null)
    u16* __restrict__ partial)       // GH x NNODE u16 (may be null)
{
    constexpr int K    = KS * 32;
    constexpr int KCHU = (K > 128) ? 128 : K;
    constexpr int KC   = KCHU / 32;
    constexpr int NCH  = K / KCHU;
    constexpr int P    = KCHU + 8;
    constexpr int ROWS = NT * 16;
    constexpr int CW   = NT * 16 + 1;
    constexpr int BSZ  = ROWS * P * 2;
    constexpr int ASZ  = 64 * CW * 4;
    constexpr int SMEM = BSZ > ASZ ? BSZ : ASZ;   // 34816 >= 25000 hist bytes
    __shared__ __align__(16) char smem[SMEM];

    // deg-partial role: LDS histogram (u16 pair packed per u32), NO fabric atomics
    if (ei && blockIdx.x >= NTILE) {
        int g = blockIdx.x - NTILE;               // 0..GH-1
        u32* hist = (u32*)smem;
        const long long e0 = (long long)g * NEDGE / GH;
        const long long e1 = (long long)(g + 1) * NEDGE / GH;
        u16* part = partial + (long long)g * NNODE;
        for (int pass = 0; pass < NPASS; ++pass) {
            const int nbase = pass * NRNG;
            for (int wi = threadIdx.x; wi < NWORD; wi += 256) hist[wi] = 0;
            __syncthreads();
            for (long long e = e0 + threadIdx.x; e < e1; e += 256) {
                int d = ei[NEDGE + e];
                int r = d - nbase;
                if ((unsigned)r < (unsigned)NRNG)
                    atomicAdd(&hist[r >> 1], 1u << ((r & 1) * 16));
            }
            __syncthreads();
            for (int wi = threadIdx.x; wi < NWORD; wi += 256)
                *(u32*)&part[nbase + wi * 2] = hist[wi];
            __syncthreads();
        }
        return;
    }

    u16*   bl   = (u16*)smem;
    float* accL = (float*)smem;

    const int wave = threadIdx.x >> 6;
    const int lane = threadIdx.x & 63;
    const int m = lane & 15, q = lane >> 4;
    const int rowbase = blockIdx.x * 64 + wave * 16;
    const int row = rowbase + m;
    const bool rok = row < M;
    const short8 z8 = {0,0,0,0,0,0,0,0};

    short8 af[KS];
    if (AF32) {
        const float* apf = (const float*)Araw + (long long)row * K;
        #pragma unroll
        for (int k = 0; k < KS; ++k) {
            short8 t = z8;
            if (rok) {
                const float4* p = (const float4*)(apf + (k * 4 + q) * 8);
                float4 a = p[0], b = p[1];
                t[0]=(short)f2bf(a.x); t[1]=(short)f2bf(a.y); t[2]=(short)f2bf(a.z); t[3]=(short)f2bf(a.w);
                t[4]=(short)f2bf(b.x); t[5]=(short)f2bf(b.y); t[6]=(short)f2bf(b.z); t[7]=(short)f2bf(b.w);
            }
            af[k] = t;
        }
    } else {
        const short8* ap = (const short8*)((const u16*)Araw + (long long)row * K);
        #pragma unroll
        for (int k = 0; k < KS; ++k) af[k] = rok ? ap[k * 4 + q] : z8;
    }
    if (LOADACT) {
        #pragma unroll
        for (int k = 0; k < KS; ++k)
            #pragma unroll
            for (int e = 0; e < 8; ++e) {
                float f = bf2f((u16)af[k][e]);
                f = f > 0.f ? f : 0.01f * f;
                af[k][e] = (short)f2bf(f);
            }
    }

    f32x4 acc[NT];
    #pragma unroll
    for (int j = 0; j < NT; ++j) acc[j] = (f32x4){0.f,0.f,0.f,0.f};

    for (int ch = 0; ch < NCH; ++ch) {
        if (ch) __syncthreads();
        constexpr int CHUNKS = ROWS * (KCHU / 8);
        for (int t = threadIdx.x; t < CHUNKS; t += 256) {
            int r = t / (KCHU / 8), c = t - r * (KCHU / 8);
            short8 v = z8;
            if (r < Nn) v = *(const short8*)&Bt[(long long)r * K + ch * KCHU + c * 8];
            *(short8*)&bl[r * P + c * 8] = v;
        }
        __syncthreads();
        #pragma unroll
        for (int j = 0; j < NT; ++j) {
            #pragma unroll
            for (int k = 0; k < KC; ++k) {
                short8 bf_ = *(const short8*)&bl[(j * 16 + m) * P + k * 32 + q * 8];
                acc[j] = __builtin_amdgcn_mfma_f32_16x16x32_bf16(af[ch * KC + k], bf_, acc[j], 0, 0, 0);
            }
        }
    }

    __syncthreads();
    #pragma unroll
    for (int j = 0; j < NT; ++j)
        #pragma unroll
        for (int r = 0; r < 4; ++r)
            accL[(wave * 16 + q * 4 + r) * CW + j * 16 + m] = acc[j][r];
    __syncthreads();

    const int c0 = lane * 2;
    if (c0 < NT * 16) {
        float2 bv = {0.f, 0.f};
        if (bias) {
            if (c0 < Nn)     bv.x = bias[c0];
            if (c0 + 1 < Nn) bv.y = bias[c0 + 1];
        }
        #pragma unroll
        for (int rl = 0; rl < 16; ++rl) {
            int rowD = rowbase + rl;
            if (rowD >= M) continue;
            float2 v = *(const float2*)&accL[(wave * 16 + rl) * CW + c0];
            long long o = (long long)rowD * ldc + c0;
            v.x += bv.x; v.y += bv.y;
            if (EPI == 1) {
                v.x = v.x > 0.f ? v.x : 0.01f * v.x;
                v.y = v.y > 0.f ? v.y : 0.01f * v.y;
            }
            if (c0 + 1 < Nn) {
                if (outB) { ushort2 ob; ob.x = f2bf(v.x); ob.y = f2bf(v.y);
                            *(ushort2*)&outB[o] = ob; }
                if (outB8) outB8[o >> 1] = pk_fp8(v.x, v.y);
                if (outF) { *(float2*)&outF[o] = v; }
            } else if (c0 < Nn) {
                if (outB) outB[o] = f2bf(v.x);
                if (outF) outF[o] = v.x;
            }
        }
    }
}

// ---- CSR gather (fp8 in, bf16 out), wave per node (HD=64 only now) ----
template<int HD>
__global__ __launch_bounds__(256) void gather_kernel(
    const int* __restrict__ rowptr, const int* __restrict__ degi,
    const int2* __restrict__ ecsr, const float* __restrict__ dinv,
    const u32* __restrict__ g8, u16* __restrict__ aggB)
{
    int node = (blockIdx.x * 256 + threadIdx.x) >> 6;
    int lane = threadIdx.x & 63;
    if (node >= NNODE) return;
    const int qr = lane >> 4, l4 = lane & 15;
    const int r0 = rowptr[node];
    const int r1 = r0 + degi[node];
    const float dn = dinv[node];
    constexpr int EL = (HD == 128) ? 8 : 4;

    float a[EL];
    #pragma unroll
    for (int i = 0; i < EL; ++i) a[i] = 0.f;
    if (qr == 0) {
        if (HD == 128) {
            uint2 gv = ((const uint2*)g8)[(long long)node * 16 + l4];
            acc_fp8x4(a, gv.x, dn);
            acc_fp8x4(a + 4, gv.y, dn);
        } else {
            u32 gv = g8[(long long)node * 16 + l4];
            acc_fp8x4(a, gv, dn);
        }
    }

    for (int base = r0; base < r1; base += 64) {
        int idx = base + lane;
        int cs = 0; float cw = 0.f;
        if (idx < r1) { int2 ev = ecsr[idx]; cs = ev.x; cw = __int_as_float(ev.y); }
        int cnt = min(64, r1 - base);
        for (int j = 0; j < cnt; j += 16) {
            #pragma unroll
            for (int u = 0; u < 4; ++u) {
                int jj = j + u * 4 + qr;
                int   s = __shfl(cs, jj);
                float w = __shfl(cw, jj);
                if (HD == 128) {
                    uint2 gv = ((const uint2*)g8)[(long long)s * 16 + l4];
                    acc_fp8x4(a, gv.x, w);
                    acc_fp8x4(a + 4, gv.y, w);
                } else {
                    u32 gv = g8[(long long)s * 16 + l4];
                    acc_fp8x4(a, gv, w);
                }
            }
        }
    }

    #pragma unroll
    for (int i = 0; i < EL; ++i) {
        a[i] += __shfl_xor(a[i], 16);
        a[i] += __shfl_xor(a[i], 32);
    }
    if (HD == 128) {
        float v0 = (qr == 0) ? a[0] : (qr == 1) ? a[2] : (qr == 2) ? a[4] : a[6];
        float v1 = (qr == 0) ? a[1] : (qr == 1) ? a[3] : (qr == 2) ? a[5] : a[7];
        v0 *= dn; v1 *= dn;
        long long o = (long long)node * 128 + l4 * 8 + qr * 2;
        ushort2 ob; ob.x = f2bf(v0); ob.y = f2bf(v1);
        *(ushort2*)&aggB[o] = ob;
    } else {
        float v = (qr == 0) ? a[0] : (qr == 1) ? a[1] : (qr == 2) ? a[2] : a[3];
        aggB[(long long)node * 64 + l4 * 4 + qr] = f2bf(v * dn);
    }
}

// ---- FUSED gather+conv: 512 threads, 8 waves (r12-verified, 50us vs ~70 split) ----
// TAIL=0: write h_new (bf16 + fp8 shadow).
// TAIL=1: additionally fuse h2 = leaky(leaky(h_new)@w2^T + b2); only h2 hits HBM.
template<int TAIL>
__global__ __launch_bounds__(512, 3) void fconv(
    const u16* __restrict__ hA, const u32* __restrict__ g8,
    const int* __restrict__ rowptr, const int* __restrict__ degi,
    const int2* __restrict__ ecsr, const float* __restrict__ dinv,
    const u16* __restrict__ BtW, const u16* __restrict__ BtG,
    const float* __restrict__ bias,
    u16* __restrict__ outB, u16* __restrict__ outB8,
    const u16* __restrict__ w2W, const float* __restrict__ b2)
{
    constexpr int K = 128, P = 136;
    __shared__ __align__(16) char smem[52224];
    u16* bl   = (u16*)smem;              // [128][136] B tile / accW epilogue
    u16* aggT = (u16*)(smem + 34816);    // [64][136] gathered rows / h_new tile
    const int wave = threadIdx.x >> 6, lane = threadIdx.x & 63;
    const int m = lane & 15, q = lane >> 4;
    const int blockrow = blockIdx.x * 64;
    const short8 z8 = {0,0,0,0,0,0,0,0};

    // ---- gather phase: 8 nodes per wave, 4-unrolled ILP ----
    {
        const int qr = q, l4 = m;
        for (int nn = 0; nn < 8; ++nn) {
            int lr = wave * 8 + nn;
            int node = blockrow + lr;
            if (node >= NNODE) break;
            const int r0 = rowptr[node];
            const int r1 = r0 + degi[node];
            const float dn = dinv[node];
            float a[8] = {0.f,0.f,0.f,0.f,0.f,0.f,0.f,0.f};
            if (qr == 0) {
                uint2 gv = ((const uint2*)g8)[(long long)node * 16 + l4];
                acc_fp8x4(a, gv.x, dn);
                acc_fp8x4(a + 4, gv.y, dn);
            }
            for (int base = r0; base < r1; base += 64) {
                int idx = base + lane;
                int cs = 0; float cw = 0.f;
                if (idx < r1) { int2 ev = ecsr[idx]; cs = ev.x; cw = __int_as_float(ev.y); }
                int cnt = min(64, r1 - base);
                for (int j = 0; j < cnt; j += 16) {
                    #pragma unroll
                    for (int u = 0; u < 4; ++u) {
                        int jj = j + u * 4 + qr;
                        int   s = __shfl(cs, jj);
                        float w = __shfl(cw, jj);
                        uint2 gv = ((const uint2*)g8)[(long long)s * 16 + l4];
                        acc_fp8x4(a, gv.x, w);
                        acc_fp8x4(a + 4, gv.y, w);
                    }
                }
            }
            #pragma unroll
            for (int i = 0; i < 8; ++i) {
                a[i] += __shfl_xor(a[i], 16);
                a[i] += __shfl_xor(a[i], 32);
            }
            float v0 = (qr == 0) ? a[0] : (qr == 1) ? a[2] : (qr == 2) ? a[4] : a[6];
            float v1 = (qr == 0) ? a[1] : (qr == 1) ? a[3] : (qr == 2) ? a[5] : a[7];
            v0 *= dn; v1 *= dn;
            ushort2 ob; ob.x = f2bf(v0); ob.y = f2bf(v1);
            *(ushort2*)&aggT[lr * P + l4 * 8 + qr * 2] = ob;
        }
    }
    __syncthreads();      // aggT complete for all 64 rows

    // ---- conv phase: 4 row-quarters x 2 col-halves ----
    const int nh = wave >> 2;                 // col-half
    const int rowbase = blockrow + (wave & 3) * 16;
    const int row = rowbase + m;
    const bool rok = row < NNODE;

    short8 af1[4], af2[4];
    {
        const short8* ap1 = (const short8*)(hA + (long long)row * K);
        #pragma unroll
        for (int k = 0; k < 4; ++k) {
            af1[k] = rok ? ap1[k * 4 + q] : z8;
            af2[k] = rok ? *(const short8*)&aggT[((wave & 3) * 16 + m) * P + k * 32 + q * 8] : z8;
        }
    }

    f32x4 acc[4];
    #pragma unroll
    for (int j = 0; j < 4; ++j) acc[j] = (f32x4){0.f,0.f,0.f,0.f};

    #pragma unroll
    for (int pass = 0; pass < 2; ++pass) {    // W then G, full [128][136] staged
        const u16* Bsrc = pass ? BtG : BtW;
        if (pass) __syncthreads();
        for (int t = threadIdx.x; t < 2048; t += 512) {
            int r = t >> 4, c = t & 15;
            *(short8*)&bl[r * P + c * 8] = *(const short8*)&Bsrc[(long long)r * K + c * 8];
        }
        __syncthreads();
        #pragma unroll
        for (int j = 0; j < 4; ++j)
            #pragma unroll
            for (int kk = 0; kk < 4; ++kk) {
                short8 b_ = *(const short8*)&bl[(nh*64 + j*16 + m) * P + kk*32 + q*8];
                acc[j] = __builtin_amdgcn_mfma_f32_16x16x32_bf16(
                    pass ? af2[kk] : af1[kk], b_, acc[j], 0, 0, 0);
            }
    }

    __syncthreads();
    float* accW = (float*)smem + wave * 16 * 65;   // 8 waves x 4160B = 33280
    #pragma unroll
    for (int j = 0; j < 4; ++j)
        #pragma unroll
        for (int r = 0; r < 4; ++r)
            accW[(q*4 + r) * 65 + j*16 + m] = acc[j][r];

    const int hw = lane >> 5;
    const int c0 = (lane & 31) * 2;
    float2 bv = {bias[nh*64 + c0], bias[nh*64 + c0 + 1]};

    if (TAIL == 0) {
        #pragma unroll
        for (int rl8 = 0; rl8 < 8; ++rl8) {
            int rl = hw * 8 + rl8;
            int rowD = rowbase + rl;
            if (rowD >= NNODE) continue;
            float2 v = *(const float2*)&accW[rl * 65 + c0];
            long long o = (long long)rowD * 128 + nh*64 + c0;
            ushort2 hh = *(const ushort2*)&hA[o];
            float n0 = bf2f(hh.x) + EPSC * ftanh(v.x + bv.x);
            float n1 = bf2f(hh.y) + EPSC * ftanh(v.y + bv.y);
            ushort2 ob; ob.x = f2bf(n0); ob.y = f2bf(n1);
            *(ushort2*)&outB[o] = ob;
            outB8[o >> 1] = pk_fp8(n0, n1);
        }
        return;
    }

    // ---- TAIL=1: leaky(h_new) -> aggT (gather tile is dead), no HBM write ----
    #pragma unroll
    for (int rl8 = 0; rl8 < 8; ++rl8) {
        int rl = hw * 8 + rl8;
        int rowD = rowbase + rl;
        float n0 = 0.f, n1 = 0.f;
        if (rowD < NNODE) {
            float2 v = *(const float2*)&accW[rl * 65 + c0];
            long long o = (long long)rowD * 128 + nh*64 + c0;
            ushort2 hh = *(const ushort2*)&hA[o];
            n0 = bf2f(hh.x) + EPSC * ftanh(v.x + bv.x);
            n1 = bf2f(hh.y) + EPSC * ftanh(v.y + bv.y);
            n0 = n0 > 0.f ? n0 : 0.01f * n0;
            n1 = n1 > 0.f ? n1 : 0.01f * n1;
        }
        ushort2 ob; ob.x = f2bf(n0); ob.y = f2bf(n1);
        *(ushort2*)&aggT[((wave & 3) * 16 + rl) * P + nh*64 + c0] = ob;
    }
    __syncthreads();      // full [64][128] h_new tile ready (both col-halves)

    // A-frags from h_new tile (full K=128)
    short8 af3[4];
    #pragma unroll
    for (int k = 0; k < 4; ++k)
        af3[k] = *(const short8*)&aggT[((wave & 3) * 16 + m) * P + k * 32 + q * 8];

    // stage w2 [64,128] bf16 into bl (accW region dead: all reads done pre-sync)
    for (int t = threadIdx.x; t < 1024; t += 512) {
        int r = t >> 4, c = t & 15;
        *(short8*)&bl[r * P + c * 8] = *(const short8*)&w2W[(long long)r * K + c * 8];
    }
    __syncthreads();

    // h2 GEMM: wave computes rows (wave&3)*16 x cols nh*32..+32 (NT=2)
    f32x4 acc2[2];
    #pragma unroll
    for (int j = 0; j < 2; ++j) acc2[j] = (f32x4){0.f,0.f,0.f,0.f};
    #pragma unroll
    for (int j = 0; j < 2; ++j)
        #pragma unroll
        for (int k = 0; k < 4; ++k) {
            short8 b_ = *(const short8*)&bl[(nh*32 + j*16 + m) * P + k*32 + q*8];
            acc2[j] = __builtin_amdgcn_mfma_f32_16x16x32_bf16(af3[k], b_, acc2[j], 0, 0, 0);
        }

    __syncthreads();      // w2 reads done; bl region repurposed for accW2
    float* accW2 = (float*)smem + wave * 16 * 33;   // 8 waves x 2112B = 16896
    #pragma unroll
    for (int j = 0; j < 2; ++j)
        #pragma unroll
        for (int r = 0; r < 4; ++r)
            accW2[(q*4 + r) * 33 + j*16 + m] = acc2[j][r];

    // per-wave 16x32 epilogue: lane covers 4 rows x 2 cols
    const int r4 = lane >> 4;                 // row group 0..3 (4 rows each)
    const int c2 = (lane & 15) * 2;           // local col 0..30
    float2 bv2 = {b2[nh*32 + c2], b2[nh*32 + c2 + 1]};
    #pragma unroll
    for (int rr = 0; rr < 4; ++rr) {
        int rl = r4 * 4 + rr;
        int rowD = rowbase + rl;
        if (rowD >= NNODE) continue;
        float2 v = *(const float2*)&accW2[rl * 33 + c2];
        v.x += bv2.x; v.y += bv2.y;
        v.x = v.x > 0.f ? v.x : 0.01f * v.x;
        v.y = v.y > 0.f ? v.y : 0.01f * v.y;
        long long o = (long long)rowD * 64 + nh*32 + c2;
        ushort2 ob; ob.x = f2bf(v.x); ob.y = f2bf(v.y);
        *(ushort2*)&outB[o] = ob;
        outB8[o >> 1] = pk_fp8(v.x, v.y);
    }
}

// ---- fused conv2 + FC + log_softmax (agg from global) ----
__global__ __launch_bounds__(256, 4) void conv2fc(
    const u16* __restrict__ hA,      // h2 [M,64] bf16
    const u16* __restrict__ gA,      // Âh2 [M,64] bf16 (from gather<64>)
    const u16* __restrict__ BtW, const u16* __restrict__ BtG,
    const float* __restrict__ bias,
    const u16* __restrict__ wfcB, const float* __restrict__ bfc,
    float* __restrict__ outF, int M)
{
    constexpr int K  = 64, NT = 4, KS = 2;
    constexpr int P  = K + 8;                 // 72
    constexpr int CW = 65;
    constexpr int R1 = 64 * CW * 4;           // 16640
    __shared__ __align__(16) char smem[R1 + 64 * P * 2];
    u16*   bl   = (u16*)smem;
    float* accL = (float*)smem;
    u16*   aggT = (u16*)(smem + R1);

    const int wave = threadIdx.x >> 6;
    const int lane = threadIdx.x & 63;
    const int m = lane & 15, q = lane >> 4;
    const int rowbase = blockIdx.x * 64 + wave * 16;
    const int row = rowbase + m;
    const bool rok = row < M;
    const short8 z8 = {0,0,0,0,0,0,0,0};

    short8 af1[KS], af2[KS];
    {
        const short8* ap1 = (const short8*)(hA + (long long)row * K);
        const short8* ap2 = (const short8*)(gA + (long long)row * K);
        #pragma unroll
        for (int k = 0; k < KS; ++k) {
            af1[k] = rok ? ap1[k * 4 + q] : z8;
            af2[k] = rok ? ap2[k * 4 + q] : z8;
        }
    }

    f32x4 acc[NT];
    #pragma unroll
    for (int j = 0; j < NT; ++j) acc[j] = (f32x4){0.f,0.f,0.f,0.f};

    #pragma unroll
    for (int pass = 0; pass < 2; ++pass) {
        const u16* Bcur = pass ? BtG : BtW;
        if (pass) __syncthreads();
        constexpr int CHUNKS = 64 * (K / 8);      // 512
        for (int t = threadIdx.x; t < CHUNKS; t += 256) {
            int r = t >> 3, c = t & 7;
            *(short8*)&bl[r * P + c * 8] = *(const short8*)&Bcur[(long long)r * K + c * 8];
        }
        __syncthreads();
        #pragma unroll
        for (int j = 0; j < NT; ++j)
            #pragma unroll
            for (int k = 0; k < KS; ++k) {
                short8 bf_ = *(const short8*)&bl[(j * 16 + m) * P + k * 32 + q * 8];
                acc[j] = __builtin_amdgcn_mfma_f32_16x16x32_bf16(
                    pass ? af2[k] : af1[k], bf_, acc[j], 0, 0, 0);
            }
    }

    __syncthreads();
    #pragma unroll
    for (int j = 0; j < NT; ++j)
        #pragma unroll
        for (int r = 0; r < 4; ++r)
            accL[(wave * 16 + q * 4 + r) * CW + j * 16 + m] = acc[j][r];
    __syncthreads();

    // epilogue1: h2n = h2 + eps*tanh(acc + b_a2) -> aggT tile
    {
        const int c0 = lane * 2;
        float2 bv = {bias[c0 & 63], bias[(c0 + 1) & 63]};
        if (c0 < 64) {
            #pragma unroll
            for (int rl = 0; rl < 16; ++rl) {
                int rowD = rowbase + rl;
                float n0 = 0.f, n1 = 0.f;
                if (rowD < M) {
                    float2 v = *(const float2*)&accL[(wave * 16 + rl) * CW + c0];
                    long long o = (long long)rowD * 64 + c0;
                    ushort2 hh = *(const ushort2*)&hA[o];
                    n0 = bf2f(hh.x) + EPSC * ftanh(v.x + bv.x);
                    n1 = bf2f(hh.y) + EPSC * ftanh(v.y + bv.y);
                }
                ushort2 ob; ob.x = f2bf(n0); ob.y = f2bf(n1);
                *(ushort2*)&aggT[(wave * 16 + rl) * P + c0] = ob;
            }
        }
    }
    __syncthreads();   // accL region about to be restaged with wfc

    short8 af4[KS];
    #pragma unroll
    for (int k = 0; k < KS; ++k)
        af4[k] = *(const short8*)&aggT[(wave * 16 + m) * P + k * 32 + q * 8];

    // stage wfc [40,64], zero-pad rows 40..47 (NT=3 -> 48 rows)
    {
        constexpr int CHF = 48 * 8;
        for (int t = threadIdx.x; t < CHF; t += 256) {
            int r = t >> 3, c = t & 7;
            short8 v = z8;
            if (r < 40) v = *(const short8*)&wfcB[(long long)r * K + c * 8];
            *(short8*)&bl[r * P + c * 8] = v;
        }
    }
    __syncthreads();

    f32x4 acc3[3];
    #pragma unroll
    for (int j = 0; j < 3; ++j) acc3[j] = (f32x4){0.f,0.f,0.f,0.f};
    #pragma unroll
    for (int j = 0; j < 3; ++j)
        #pragma unroll
        for (int k = 0; k < KS; ++k) {
            short8 bf_ = *(const short8*)&bl[(j * 16 + m) * P + k * 32 + q * 8];
            acc3[j] = __builtin_amdgcn_mfma_f32_16x16x32_bf16(af4[k], bf_, acc3[j], 0, 0, 0);
        }

    __syncthreads();
    constexpr int CW3 = 49;
    #pragma unroll
    for (int j = 0; j < 3; ++j)
        #pragma unroll
        for (int r = 0; r < 4; ++r)
            accL[(wave * 16 + q * 4 + r) * CW3 + j * 16 + m] = acc3[j][r];
    __syncthreads();

    // fused log_softmax over 40 cols
    float mrow = 0.f, lrow = 0.f;
    if (lane < 16) {
        const float* rp = &accL[(wave * 16 + lane) * CW3];
        float mx = -1e30f;
        for (int c = 0; c < 40; ++c) mx = fmaxf(mx, rp[c] + bfc[c]);
        float s = 0.f;
        for (int c = 0; c < 40; ++c) s += expf(rp[c] + bfc[c] - mx);
        mrow = mx; lrow = logf(s);
    }
    for (int rl = 0; rl < 16; ++rl) {
        float mm = __shfl(mrow, rl);
        float ll = __shfl(lrow, rl);
        int rowD = rowbase + rl;
        if (rowD < M && lane < 40) {
            float v = accL[(wave * 16 + rl) * CW3 + lane] + bfc[lane];
            outF[(long long)rowD * 40 + lane] = v - mm - ll;
        }
    }
}

extern "C" void kernel_launch(void* const* d_in, const int* in_sizes, int n_in,
                              void* d_out, int out_size, void* d_ws, size_t ws_size,
                              hipStream_t stream) {
    const float* x     = (const float*)d_in[0];
    const int*   ei    = (const int*)d_in[1];
    const float* w_hid = (const float*)d_in[2];
    const float* b_hid = (const float*)d_in[3];
    const float* W_a1  = (const float*)d_in[4];
    const float* gcn1  = (const float*)d_in[5];
    const float* b_a1  = (const float*)d_in[6];
    const float* w2    = (const float*)d_in[7];
    const float* b2    = (const float*)d_in[8];
    const float* W_a2  = (const float*)d_in[9];
    const float* gcn2  = (const float*)d_in[10];
    const float* b_a2  = (const float*)d_in[11];
    const float* wfc   = (const float*)d_in[12];
    const float* bfc   = (const float*)d_in[13];
    float* ws = (float*)d_ws;
    float* out = (float*)d_out;

    float* dinv   = ws + O_DINV;
    int*   degi   = (int*)(ws + O_DEGI);
    int*   rowptr = (int*)(ws + O_ROWPTR);
    int*   gcur   = (int*)(ws + O_GCUR);
    int2*  ecsr   = (int2*)(ws + O_ECSR);
    u16* whB  = (u16*)(ws + O_WHB);
    u16* g1tB = (u16*)(ws + O_G1TB);
    u16* aw1B = (u16*)(ws + O_AW1B);
    u16* w2B  = (u16*)(ws + O_W2B);
    u16* aw2B = (u16*)(ws + O_AW2B);
    u16* g2tB = (u16*)(ws + O_G2TB);
    u16* wfcB = (u16*)(ws + O_WFCB);
    u16* aggB = (u16*)(ws + O_AGGB);
    u16* hB0  = (u16*)(ws + O_HB0);
    u16* hB1  = (u16*)(ws + O_HB1);
    u16* s0   = (u16*)(ws + O_S0);
    u16* s1   = (u16*)(ws + O_S1);
    u16* part = (u16*)(ws + O_PART);
    u16* base16 = (u16*)(ws + O_BASE);

    prep_kernel<<<(84481 + 255) / 256, 256, 0, stream>>>(
        w_hid, W_a1, gcn1, w2, W_a2, gcn2, wfc, ws);

    const int gatherBlocks = (NNODE * 64 + 255) / 256;   // 12500 (wave per node)

    // h = leaky_relu(x @ w_hid^T + b_hid) -> hB0 (+fp8 shadow s0);
    // blocks >= NTILE build per-slice degree partials via LDS histograms
    mgemm<8, 8, 1, 0, 1><<<NTILE + GH, 256, 0, stream>>>(
        x, whB, b_hid, nullptr, hB0, s0, NNODE, 128, 128, ei, part);

    alloc_kernel<<<(NNODE + 255) / 256, 256, 0, stream>>>(
        part, dinv, degi, rowptr, base16, gcur);
    fill_kernel<<<GH * NPASS, 256, 0, stream>>>(ei, dinv, rowptr, base16, ecsr);

    // conv1: all 3 iterations fused gather+conv; iter3 additionally fuses h2 GEMM
    fconv<0><<<NTILE, 512, 0, stream>>>(hB0, (const u32*)s0, rowptr, degi, ecsr, dinv,
                                        aw1B, g1tB, b_a1, hB1, s1, nullptr, nullptr);
    fconv<0><<<NTILE, 512, 0, stream>>>(hB1, (const u32*)s1, rowptr, degi, ecsr, dinv,
                                        aw1B, g1tB, b_a1, hB0, s0, nullptr, nullptr);
    fconv<1><<<NTILE, 512, 0, stream>>>(hB0, (const u32*)s0, rowptr, degi, ecsr, dinv,
                                        aw1B, g1tB, b_a1, hB1, s1, w2B, b2);

    // conv2 + fc + log_softmax (gather<64> stays split: conv2fc is 4-wave shaped)
    gather_kernel<64><<<gatherBlocks, 256, 0, stream>>>(
        rowptr, degi, ecsr, dinv, (const u32*)s1, aggB);
    conv2fc<<<NTILE, 256, 0, stream>>>(
        hB1, aggB, aw2B, g2tB, b_a2, wfcB, bfc, out, NNODE);
}